// Round 1
// baseline (10234.768 us; speedup 1.0000x reference)
//
#include <hip/hip_runtime.h>
#include <hip/hip_bf16.h>
#include <math.h>

#define D_   1024
#define H_   16
#define DK_  64
#define DV_  128
#define L_   3
#define FFN_ 4096
#define S_   1024
#define B_   4

// ---------------------------------------------------------------- embed
__global__ __launch_bounds__(256) void k_embed(const int* __restrict__ tokens,
                                               const float* __restrict__ emb,
                                               float* __restrict__ h) {
    int i = blockIdx.x * 256 + threadIdx.x;       // B*S*D = 4M threads
    int d  = i & (D_ - 1);
    int bs = i >> 10;
    int s  = bs & (S_ - 1);
    int b  = bs >> 10;
    int tok = (s == 0) ? 0 : tokens[b * S_ + s - 1];
    h[i] = emb[tok * D_ + d] * 32.0f;             // sqrt(1024) = 32
}

// ---------------------------------------------------------------- layernorm (rows of 1024)
__global__ __launch_bounds__(256) void k_ln(const float* __restrict__ x,
                                            const float* __restrict__ s,
                                            const float* __restrict__ b,
                                            float* __restrict__ y, float eps) {
    int row = blockIdx.x;
    int t = threadIdx.x;
    const float* xr = x + (size_t)row * D_;
    float4 xv = *(const float4*)&xr[t * 4];
    float sum = xv.x + xv.y + xv.z + xv.w;
    float ssq = xv.x * xv.x + xv.y * xv.y + xv.z * xv.z + xv.w * xv.w;
    __shared__ float sm1[4], sm2[4];
    #pragma unroll
    for (int off = 32; off > 0; off >>= 1) {
        sum += __shfl_down(sum, off, 64);
        ssq += __shfl_down(ssq, off, 64);
    }
    int lane = t & 63, w = t >> 6;
    if (lane == 0) { sm1[w] = sum; sm2[w] = ssq; }
    __syncthreads();
    sum = sm1[0] + sm1[1] + sm1[2] + sm1[3];
    ssq = sm2[0] + sm2[1] + sm2[2] + sm2[3];
    float mean = sum * (1.0f / D_);
    float var  = ssq * (1.0f / D_) - mean * mean;
    float inv  = 1.0f / sqrtf(var + eps);
    float4 sv = *(const float4*)&s[t * 4];
    float4 bv = *(const float4*)&b[t * 4];
    float4 out;
    out.x = (xv.x - mean) * inv * sv.x + bv.x;
    out.y = (xv.y - mean) * inv * sv.y + bv.y;
    out.z = (xv.z - mean) * inv * sv.z + bv.z;
    out.w = (xv.w - mean) * inv * sv.w + bv.w;
    *(float4*)&y[(size_t)row * D_ + t * 4] = out;
}

// ---------------------------------------------------------------- tiled fp32 GEMM
// C[M,N] = A[M,K] @ B[K,N]  (+bias if flags&2) (+C if flags&1)
__global__ __launch_bounds__(256) void k_gemm(const float* __restrict__ A,
                                              const float* __restrict__ B,
                                              const float* __restrict__ bias,
                                              float* __restrict__ C,
                                              int M, int N, int K, int flags) {
    __shared__ float As[16][68];   // As[k][m], padded
    __shared__ float Bs[16][64];   // Bs[k][n]
    int t  = threadIdx.x;
    int n0 = blockIdx.x * 64, m0 = blockIdx.y * 64;
    int tx = t & 15, ty = t >> 4;
    int am = t >> 2;             // 0..63
    int ak = (t & 3) * 4;        // 0,4,8,12
    int bk = t >> 4;             // 0..15
    int bn = (t & 15) * 4;
    float c[4][4] = {};
    for (int k0 = 0; k0 < K; k0 += 16) {
        float4 av = *(const float4*)&A[(size_t)(m0 + am) * K + k0 + ak];
        float4 bv = *(const float4*)&B[(size_t)(k0 + bk) * N + n0 + bn];
        As[ak + 0][am] = av.x;
        As[ak + 1][am] = av.y;
        As[ak + 2][am] = av.z;
        As[ak + 3][am] = av.w;
        *(float4*)&Bs[bk][bn] = bv;
        __syncthreads();
        #pragma unroll
        for (int kk = 0; kk < 16; kk++) {
            float4 a4 = *(const float4*)&As[kk][ty * 4];
            float4 b4 = *(const float4*)&Bs[kk][tx * 4];
            float a[4] = {a4.x, a4.y, a4.z, a4.w};
            float b[4] = {b4.x, b4.y, b4.z, b4.w};
            #pragma unroll
            for (int i = 0; i < 4; i++)
                #pragma unroll
                for (int j = 0; j < 4; j++)
                    c[i][j] = fmaf(a[i], b[j], c[i][j]);
        }
        __syncthreads();
    }
    #pragma unroll
    for (int i = 0; i < 4; i++) {
        int m = m0 + ty * 4 + i;
        #pragma unroll
        for (int j = 0; j < 4; j++) {
            int n = n0 + tx * 4 + j;
            float val = c[i][j];
            if (flags & 2) val += bias[n];
            if (flags & 1) val += C[(size_t)m * N + n];
            C[(size_t)m * N + n] = val;
        }
    }
}

// ---------------------------------------------------------------- RoPE (in place), optional scale
__global__ __launch_bounds__(256) void k_rope(float* __restrict__ x, float scale) {
    int i = blockIdx.x * 256 + threadIdx.x;       // B*S*H*32 = 2M pair-threads
    int pair = i & 31;
    int bs   = i >> 9;                            // 512 pairs per row
    int hh   = (i >> 5) & 15;
    int sIdx = bs & (S_ - 1);
    float ang = expf(-(float)pair * (1.0f / 31.0f) * 9.210340372f); // ln(10000)
    float ph  = (float)sIdx * ang;
    float sn, cs;
    sincosf(ph, &sn, &cs);
    size_t base = (size_t)bs * D_ + hh * DK_ + 2 * pair;
    float x1 = x[base], x2 = x[base + 1];
    x[base]     = (x1 * cs - x2 * sn) * scale;
    x[base + 1] = (x2 * cs + x1 * sn) * scale;
}

// ---------------------------------------------------------------- retention attention
// One block per (b, h, 64-row tile). Flash-style over 32-col m tiles.
__global__ __launch_bounds__(256) void k_attn(const float* __restrict__ q,
                                              const float* __restrict__ kbuf,
                                              const float* __restrict__ v,
                                              float* __restrict__ o) {
    int bid = blockIdx.x;                 // ((b*16 + h)*16 + nt)
    int nt = bid & 15;
    int bh = bid >> 4;
    int hh = bh & 15;
    int b  = bh >> 4;
    int t  = threadIdx.x;
    int n0 = nt * 64;

    __shared__ float Qs[64][68];
    __shared__ float Ks[32][68];
    __shared__ float Vs[32][128];
    __shared__ float Ss[64][33];
    __shared__ float rowAbs[64];
    __shared__ float rnorm_s[64];

    const float* qbase = q    + ((size_t)(b * S_ + n0)) * D_ + hh * DK_;
    const float* kbase = kbuf + ((size_t)(b * S_)) * D_ + hh * DK_;
    const float* vbase = v    + ((size_t)(b * S_)) * (2 * D_) + hh * DV_;

    for (int e = t; e < 1024; e += 256) {
        int r = e >> 4, d4 = e & 15;
        *(float4*)&Qs[r][d4 * 4] = *(const float4*)&qbase[(size_t)r * D_ + d4 * 4];
    }
    double gd   = 1.0 - exp2((double)(-5 - hh));
    double l2gd = log2(gd);
    float  l2g  = (float)l2gd;
    if (t < 64) {
        int n = n0 + t;
        double rowsum = (1.0 - exp2(l2gd * (double)(n + 1))) / (1.0 - gd);
        rnorm_s[t] = (float)(1.0 / sqrt(rowsum));
        rowAbs[t]  = 0.0f;
    }
    float oacc[32];
    #pragma unroll
    for (int j = 0; j < 32; j++) oacc[j] = 0.0f;

    int r0  = (t & 15) * 4;     // phase1: 4 rows
    int mm0 = (t >> 4) * 2;     // phase1: 2 cols
    int pr  = t & 63;           // phase2: row
    int pc  = t >> 6;           // phase2: col group (0..3) * 32

    int mtiles = 2 * nt + 2;
    for (int mt = 0; mt < mtiles; mt++) {
        int m0 = mt * 32;
        __syncthreads();  // protect Ks/Vs/Ss from prior-iter readers (also covers Qs/rnorm init)
        for (int e = t; e < 512; e += 256) {
            int mm = e >> 4, d4 = e & 15;
            *(float4*)&Ks[mm][d4 * 4] = *(const float4*)&kbase[(size_t)(m0 + mm) * D_ + d4 * 4];
        }
        for (int e = t; e < 1024; e += 256) {
            int mm = e >> 5, d4 = e & 31;
            *(float4*)&Vs[mm][d4 * 4] = *(const float4*)&vbase[(size_t)(m0 + mm) * (2 * D_) + d4 * 4];
        }
        __syncthreads();
        // phase 1: scores (64x32) = Q(64x64) @ K^T(64x32), each thread 4x2
        float acc[4][2] = {};
        #pragma unroll
        for (int d4 = 0; d4 < 16; d4++) {
            float4 ka0 = *(const float4*)&Ks[mm0][d4 * 4];
            float4 ka1 = *(const float4*)&Ks[mm0 + 1][d4 * 4];
            #pragma unroll
            for (int i = 0; i < 4; i++) {
                float4 qa = *(const float4*)&Qs[r0 + i][d4 * 4];
                acc[i][0] += qa.x * ka0.x + qa.y * ka0.y + qa.z * ka0.z + qa.w * ka0.w;
                acc[i][1] += qa.x * ka1.x + qa.y * ka1.y + qa.z * ka1.z + qa.w * ka1.w;
            }
        }
        #pragma unroll
        for (int i = 0; i < 4; i++) {
            int n = n0 + r0 + i;
            #pragma unroll
            for (int j = 0; j < 2; j++) {
                int m = m0 + mm0 + j;
                float dm = (n >= m) ? exp2f((float)(n - m) * l2g) * rnorm_s[r0 + i] : 0.0f;
                Ss[r0 + i][mm0 + j] = acc[i][j] * dm;
            }
        }
        __syncthreads();
        if (t < 64) {
            float s_ = 0.0f;
            #pragma unroll
            for (int mm = 0; mm < 32; mm++) s_ += fabsf(Ss[t][mm]);
            rowAbs[t] += s_;
        }
        // phase 2: oacc += S_tile @ V_tile
        #pragma unroll
        for (int mm = 0; mm < 32; mm++) {
            float sv = Ss[pr][mm];
            const float4* vr = (const float4*)&Vs[mm][pc * 32];
            #pragma unroll
            for (int j4 = 0; j4 < 8; j4++) {
                float4 vv = vr[j4];
                oacc[j4 * 4 + 0] = fmaf(sv, vv.x, oacc[j4 * 4 + 0]);
                oacc[j4 * 4 + 1] = fmaf(sv, vv.y, oacc[j4 * 4 + 1]);
                oacc[j4 * 4 + 2] = fmaf(sv, vv.z, oacc[j4 * 4 + 2]);
                oacc[j4 * 4 + 3] = fmaf(sv, vv.w, oacc[j4 * 4 + 3]);
            }
        }
    }
    __syncthreads();
    float sc = 1.0f / fmaxf(rowAbs[pr], 1.0f);
    float* obase = o + ((size_t)(b * S_ + n0 + pr)) * (2 * D_) + hh * DV_ + pc * 32;
    #pragma unroll
    for (int j4 = 0; j4 < 8; j4++) {
        float4 ov;
        ov.x = oacc[j4 * 4 + 0] * sc;
        ov.y = oacc[j4 * 4 + 1] * sc;
        ov.z = oacc[j4 * 4 + 2] * sc;
        ov.w = oacc[j4 * 4 + 3] * sc;
        *(float4*)&obase[j4 * 4] = ov;
    }
}

// ---------------------------------------------------------------- RMS-norm over DV + silu gate (in place on o)
__global__ __launch_bounds__(128) void k_rmsgate(float* __restrict__ o,
                                                 const float* __restrict__ g) {
    size_t base = (size_t)blockIdx.x * 128;   // rows = B*S*H, o layout (bs, h*128) contiguous
    int t = threadIdx.x;
    float val = o[base + t];
    float gv  = g[base + t];
    float ss = val * val;
    #pragma unroll
    for (int off = 32; off > 0; off >>= 1) ss += __shfl_down(ss, off, 64);
    __shared__ float sm[2];
    if ((t & 63) == 0) sm[t >> 6] = ss;
    __syncthreads();
    ss = sm[0] + sm[1];
    float rms = 1.0f / sqrtf(ss * (1.0f / 128.0f) + 1e-6f);
    float sig = 1.0f / (1.0f + expf(-gv));
    o[base + t] = gv * sig * val * rms;
}

// ---------------------------------------------------------------- gelu (tanh approx), in place, float4
__global__ __launch_bounds__(256) void k_gelu(float* __restrict__ x, int n4) {
    int i = blockIdx.x * 256 + threadIdx.x;
    if (i >= n4) return;
    float4 v = ((float4*)x)[i];
    float* p = (float*)&v;
    #pragma unroll
    for (int j = 0; j < 4; j++) {
        float u = p[j];
        p[j] = 0.5f * u * (1.0f + tanhf(0.7978845608f * (u + 0.044715f * u * u * u)));
    }
    ((float4*)x)[i] = v;
}

// ---------------------------------------------------------------- final LN + logits (V=2) + log_softmax
__global__ __launch_bounds__(256) void k_final(const float* __restrict__ x,
                                               const float* __restrict__ s,
                                               const float* __restrict__ b,
                                               const float* __restrict__ Wout,
                                               float* __restrict__ out) {
    int row = blockIdx.x;
    int t = threadIdx.x;
    const float* xr = x + (size_t)row * D_;
    float4 xv = *(const float4*)&xr[t * 4];
    float sum = xv.x + xv.y + xv.z + xv.w;
    float ssq = xv.x * xv.x + xv.y * xv.y + xv.z * xv.z + xv.w * xv.w;
    __shared__ float sm1[4], sm2[4];
    #pragma unroll
    for (int off = 32; off > 0; off >>= 1) {
        sum += __shfl_down(sum, off, 64);
        ssq += __shfl_down(ssq, off, 64);
    }
    int lane = t & 63, w = t >> 6;
    if (lane == 0) { sm1[w] = sum; sm2[w] = ssq; }
    __syncthreads();
    sum = sm1[0] + sm1[1] + sm1[2] + sm1[3];
    ssq = sm2[0] + sm2[1] + sm2[2] + sm2[3];
    float mean = sum * (1.0f / D_);
    float var  = ssq * (1.0f / D_) - mean * mean;
    float inv  = 1.0f / sqrtf(var + 1e-5f);
    float4 sv = *(const float4*)&s[t * 4];
    float4 bv = *(const float4*)&b[t * 4];
    float ln[4];
    ln[0] = (xv.x - mean) * inv * sv.x + bv.x;
    ln[1] = (xv.y - mean) * inv * sv.y + bv.y;
    ln[2] = (xv.z - mean) * inv * sv.z + bv.z;
    ln[3] = (xv.w - mean) * inv * sv.w + bv.w;
    float l0 = 0.0f, l1 = 0.0f;
    #pragma unroll
    for (int i = 0; i < 4; i++) {
        int d = t * 4 + i;
        l0 += ln[i] * Wout[d * 2 + 0];
        l1 += ln[i] * Wout[d * 2 + 1];
    }
    #pragma unroll
    for (int off = 32; off > 0; off >>= 1) {
        l0 += __shfl_down(l0, off, 64);
        l1 += __shfl_down(l1, off, 64);
    }
    __syncthreads();   // before reusing sm1/sm2
    if (lane == 0) { sm1[w] = l0; sm2[w] = l1; }
    __syncthreads();
    if (t == 0) {
        l0 = sm1[0] + sm1[1] + sm1[2] + sm1[3];
        l1 = sm2[0] + sm2[1] + sm2[2] + sm2[3];
        float mx  = fmaxf(l0, l1);
        float lse = mx + logf(expf(l0 - mx) + expf(l1 - mx));
        out[(size_t)row * 2 + 0] = l0 - lse;
        out[(size_t)row * 2 + 1] = l1 - lse;
    }
}

// ---------------------------------------------------------------- launch
extern "C" void kernel_launch(void* const* d_in, const int* in_sizes, int n_in,
                              void* d_out, int out_size, void* d_ws, size_t ws_size,
                              hipStream_t stream) {
    const int*   tokens = (const int*)d_in[0];
    const float* emb    = (const float*)d_in[1];
    const float* Wq     = (const float*)d_in[2];
    const float* Wk     = (const float*)d_in[3];
    const float* Wv     = (const float*)d_in[4];
    const float* Wg     = (const float*)d_in[5];
    const float* Wo     = (const float*)d_in[6];
    const float* ln1_s  = (const float*)d_in[7];
    const float* ln1_b  = (const float*)d_in[8];
    const float* ln2_s  = (const float*)d_in[9];
    const float* ln2_b  = (const float*)d_in[10];
    const float* W1     = (const float*)d_in[11];
    const float* b1     = (const float*)d_in[12];
    const float* W2     = (const float*)d_in[13];
    const float* b2     = (const float*)d_in[14];
    const float* lnf_s  = (const float*)d_in[15];
    const float* lnf_b  = (const float*)d_in[16];
    const float* Wout   = (const float*)d_in[17];

    float* ws = (float*)d_ws;
    const size_t M1 = 1u << 20;
    float* h  = ws;             // 4M floats
    float* x1 = ws + 4 * M1;    // 4M
    float* q  = ws + 8 * M1;    // 4M
    float* kk = ws + 12 * M1;   // 4M
    float* v  = ws + 16 * M1;   // 8M
    float* g  = ws + 24 * M1;   // 8M
    float* o  = ws + 32 * M1;   // 8M
    float* f1 = ws + 8 * M1;    // 16M, overlays dead q/kk/v during FFN

    k_embed<<<16384, 256, 0, stream>>>(tokens, emb, h);

    dim3 g16(16, 64), g32(32, 64), g64(64, 64);
    for (int l = 0; l < L_; l++) {
        k_ln<<<4096, 256, 0, stream>>>(h, ln1_s + l * D_, ln1_b + l * D_, x1, 1e-5f);
        k_gemm<<<g16, 256, 0, stream>>>(x1, Wq + (size_t)l * D_ * D_, nullptr, q, 4096, 1024, 1024, 0);
        k_gemm<<<g16, 256, 0, stream>>>(x1, Wk + (size_t)l * D_ * D_, nullptr, kk, 4096, 1024, 1024, 0);
        k_gemm<<<g32, 256, 0, stream>>>(x1, Wv + (size_t)l * D_ * 2 * D_, nullptr, v, 4096, 2048, 1024, 0);
        k_gemm<<<g32, 256, 0, stream>>>(x1, Wg + (size_t)l * D_ * 2 * D_, nullptr, g, 4096, 2048, 1024, 0);
        k_rope<<<8192, 256, 0, stream>>>(q, 1.0f);
        k_rope<<<8192, 256, 0, stream>>>(kk, 0.125f);       // DK^-0.5
        k_attn<<<1024, 256, 0, stream>>>(q, kk, v, o);
        k_rmsgate<<<65536, 128, 0, stream>>>(o, g);
        k_gemm<<<g16, 256, 0, stream>>>(o, Wo + (size_t)l * 2 * D_ * D_, nullptr, h, 4096, 1024, 2048, 1);
        k_ln<<<4096, 256, 0, stream>>>(h, ln2_s + l * D_, ln2_b + l * D_, x1, 1e-5f);
        k_gemm<<<g64, 256, 0, stream>>>(x1, W1 + (size_t)l * D_ * FFN_, b1 + l * FFN_, f1, 4096, 4096, 1024, 2);
        k_gelu<<<16384, 256, 0, stream>>>(f1, 4 * 1024 * 1024);
        k_gemm<<<g16, 256, 0, stream>>>(f1, W2 + (size_t)l * FFN_ * D_, b2 + l * D_, h, 4096, 1024, 4096, 3);
    }
    k_final<<<4096, 256, 0, stream>>>(h, lnf_s, lnf_b, Wout, (float*)d_out);
}

// Round 3
// 1875.068 us; speedup vs baseline: 5.4583x; 5.4583x over previous
//
#include <hip/hip_runtime.h>
#include <hip/hip_bf16.h>
#include <math.h>
#include <stdint.h>

#define D_   1024
#define H_   16
#define DK_  64
#define DV_  128
#define L_   3
#define FFN_ 4096
#define S_   1024
#define B_   4

typedef __attribute__((ext_vector_type(8))) _Float16 f16x8;
typedef __attribute__((ext_vector_type(4))) _Float16 f16x4;
typedef __attribute__((ext_vector_type(4))) float f32x4;

__device__ __forceinline__ void gl2lds16(const void* g, void* l) {
    __builtin_amdgcn_global_load_lds(
        (const __attribute__((address_space(1))) void*)(uintptr_t)g,
        (__attribute__((address_space(3))) void*)(uintptr_t)l, 16, 0, 0);
}
#define MFMA16(a,b,c) __builtin_amdgcn_mfma_f32_16x16x32_f16(a,b,c,0,0,0)

// ---------------------------------------------------------------- embed (fp32 h)
__global__ __launch_bounds__(256) void k_embed(const int* __restrict__ tokens,
                                               const float* __restrict__ emb,
                                               float* __restrict__ h) {
    int i = blockIdx.x * 256 + threadIdx.x;
    int d  = i & (D_ - 1);
    int bs = i >> 10;
    int s  = bs & (S_ - 1);
    int b  = bs >> 10;
    int tok = (s == 0) ? 0 : tokens[b * S_ + s - 1];
    h[i] = emb[tok * D_ + d] * 32.0f;
}

// ---------------------------------------------------------------- layernorm -> fp16
__global__ __launch_bounds__(256) void k_ln(const float* __restrict__ x,
                                            const float* __restrict__ s,
                                            const float* __restrict__ b,
                                            _Float16* __restrict__ y) {
    int row = blockIdx.x;
    int t = threadIdx.x;
    const float* xr = x + (size_t)row * D_;
    float4 xv = *(const float4*)&xr[t * 4];
    float sum = xv.x + xv.y + xv.z + xv.w;
    float ssq = xv.x * xv.x + xv.y * xv.y + xv.z * xv.z + xv.w * xv.w;
    __shared__ float sm1[4], sm2[4];
    #pragma unroll
    for (int off = 32; off > 0; off >>= 1) {
        sum += __shfl_down(sum, off, 64);
        ssq += __shfl_down(ssq, off, 64);
    }
    int lane = t & 63, w = t >> 6;
    if (lane == 0) { sm1[w] = sum; sm2[w] = ssq; }
    __syncthreads();
    sum = sm1[0] + sm1[1] + sm1[2] + sm1[3];
    ssq = sm2[0] + sm2[1] + sm2[2] + sm2[3];
    float mean = sum * (1.0f / D_);
    float var  = ssq * (1.0f / D_) - mean * mean;
    float inv  = 1.0f / sqrtf(var + 1e-5f);
    float4 sv = *(const float4*)&s[t * 4];
    float4 bv = *(const float4*)&b[t * 4];
    f16x4 o;
    o.x = (_Float16)((xv.x - mean) * inv * sv.x + bv.x);
    o.y = (_Float16)((xv.y - mean) * inv * sv.y + bv.y);
    o.z = (_Float16)((xv.z - mean) * inv * sv.z + bv.z);
    o.w = (_Float16)((xv.w - mean) * inv * sv.w + bv.w);
    *(f16x4*)&y[(size_t)row * D_ + t * 4] = o;
}

// ---------------------------------------------------------------- weight cast+transpose: fp32 [K][N] -> fp16 [N][K]
__global__ __launch_bounds__(256) void k_wcast(const float* __restrict__ in,
                                               _Float16* __restrict__ out,
                                               int K, int N) {
    __shared__ float Ts[32][33];
    int n0 = blockIdx.x * 32, k0 = blockIdx.y * 32;
    int t = threadIdx.x;
    #pragma unroll
    for (int c = 0; c < 4; c++) {
        int e = c * 256 + t; int kr = e >> 5, nc = e & 31;
        Ts[kr][nc] = in[(size_t)(k0 + kr) * N + n0 + nc];
    }
    __syncthreads();
    #pragma unroll
    for (int c = 0; c < 4; c++) {
        int e = c * 256 + t; int nr = e >> 5, kc = e & 31;
        out[(size_t)(n0 + nr) * K + k0 + kc] = (_Float16)Ts[kc][nr];
    }
}

// ---------------------------------------------------------------- MFMA GEMM: C[M,N] = A[M,K](f16) @ Bt[N,K](f16)
// flags: 1=residual add into Cf(fp32), 2=+bias, 4=gelu, 8=write f16 Ch; default write Cf fp32
__global__ __launch_bounds__(256) void k_gemm_mfma(
    const _Float16* __restrict__ A, const _Float16* __restrict__ Bt,
    const float* __restrict__ bias, float* __restrict__ Cf,
    _Float16* __restrict__ Ch, int M, int N, int K, int flags)
{
    __shared__ __attribute__((aligned(16))) _Float16 As[128 * 32];
    __shared__ __attribute__((aligned(16))) _Float16 Bs[128 * 32];
    int t = threadIdx.x;
    int n0 = blockIdx.x * 128, m0 = blockIdx.y * 128;
    int w = t >> 6, lane = t & 63;
    int quad = lane >> 4, l16 = lane & 15;
    int wm = (w >> 1) * 64, wn = (w & 1) * 64;
    f32x4 acc[4][4] = {};
    for (int k0 = 0; k0 < K; k0 += 32) {
        __syncthreads();
        #pragma unroll
        for (int c = 0; c < 2; c++) {
            int chunk = c * 256 + t;
            int row = chunk >> 2, ko = (chunk & 3) * 8;
            gl2lds16(A  + (size_t)(m0 + row) * K + k0 + ko, As + chunk * 8);
            gl2lds16(Bt + (size_t)(n0 + row) * K + k0 + ko, Bs + chunk * 8);
        }
        __syncthreads();
        f16x8 af[4], bfr[4];
        #pragma unroll
        for (int i = 0; i < 4; i++)
            af[i] = *(const f16x8*)&As[(wm + i * 16 + l16) * 32 + quad * 8];
        #pragma unroll
        for (int j = 0; j < 4; j++)
            bfr[j] = *(const f16x8*)&Bs[(wn + j * 16 + l16) * 32 + quad * 8];
        #pragma unroll
        for (int i = 0; i < 4; i++)
            #pragma unroll
            for (int j = 0; j < 4; j++)
                acc[i][j] = MFMA16(af[i], bfr[j], acc[i][j]);
    }
    #pragma unroll
    for (int i = 0; i < 4; i++) {
        #pragma unroll
        for (int r = 0; r < 4; r++) {
            int row = m0 + wm + i * 16 + quad * 4 + r;
            #pragma unroll
            for (int j = 0; j < 4; j++) {
                int col = n0 + wn + j * 16 + l16;
                float v = acc[i][j][r];
                if (flags & 2) v += bias[col];
                if (flags & 4) v = 0.5f * v * (1.0f + tanhf(0.7978845608f * (v + 0.044715f * v * v * v)));
                if (flags & 1) { size_t idx = (size_t)row * N + col; Cf[idx] += v; }
                else if (flags & 8) Ch[(size_t)row * N + col] = (_Float16)v;
                else Cf[(size_t)row * N + col] = v;
            }
        }
    }
}

// ---------------------------------------------------------------- RoPE: fp32 in -> fp16 out, scale folded
__global__ __launch_bounds__(256) void k_rope(const float* __restrict__ x,
                                              _Float16* __restrict__ y, float scale) {
    int i = blockIdx.x * 256 + threadIdx.x;      // B*S*H*32 pair-threads
    int pair = i & 31;
    int hh = (i >> 5) & 15;
    int bs = i >> 9;
    int sIdx = bs & (S_ - 1);
    float ang = expf(-(float)pair * (1.0f / 31.0f) * 9.210340372f);
    float ph = (float)sIdx * ang;
    float sn, cs;
    sincosf(ph, &sn, &cs);
    size_t base = (size_t)bs * D_ + hh * DK_ + 2 * pair;
    float x1 = x[base], x2 = x[base + 1];
    y[base]     = (_Float16)((x1 * cs - x2 * sn) * scale);
    y[base + 1] = (_Float16)((x2 * cs + x1 * sn) * scale);
}

// ---------------------------------------------------------------- V transpose: [B][S][H][128] -> [B][H][128][S] (fp16)
__global__ __launch_bounds__(256) void k_vtrans(const _Float16* __restrict__ vb,
                                                _Float16* __restrict__ Vt) {
    int st = blockIdx.x, dt = blockIdx.y, bh = blockIdx.z;
    int hh = bh & 15, b = bh >> 4;
    __shared__ __attribute__((aligned(16))) _Float16 Ts[64][72];
    int t = threadIdx.x;
    const _Float16* src = vb + ((size_t)(b * S_ + st * 64) * H_ + hh) * DV_ + dt * 64;
    #pragma unroll
    for (int c = 0; c < 2; c++) {
        int chunk = c * 256 + t;
        int r = chunk >> 3, co = (chunk & 7) * 8;
        *(f16x8*)&Ts[r][co] = *(const f16x8*)(src + (size_t)r * (H_ * DV_) + co);
    }
    __syncthreads();
    _Float16* dst = Vt + ((size_t)bh * DV_ + dt * 64) * S_ + st * 64;
    #pragma unroll
    for (int c = 0; c < 2; c++) {
        int chunk = c * 256 + t;
        int dr = chunk >> 3, so = (chunk & 7) * 8;
        f16x8 val;
        #pragma unroll
        for (int j = 0; j < 8; j++) val[j] = Ts[so + j][dr];
        *(f16x8*)(dst + (size_t)dr * S_ + so) = val;
    }
}

// ---------------------------------------------------------------- MFMA retention attention
// grid (16 q-tiles, 64 bh), 256 threads. q,k: [B][S][H][64] f16; Vt: [B][H][128][S] f16; o: fp32 [B][S][H][128]
__global__ __launch_bounds__(256) void k_attn(const _Float16* __restrict__ qb,
                                              const _Float16* __restrict__ kb,
                                              const _Float16* __restrict__ Vt,
                                              float* __restrict__ of) {
    int nt = blockIdx.x, bh = blockIdx.y;
    int hh = bh & 15, b = bh >> 4;
    int t = threadIdx.x, w = t >> 6, lane = t & 63;
    int quad = lane >> 4, l16 = lane & 15;
    int n0 = nt * 64;

    __shared__ __attribute__((aligned(16))) _Float16 Qs[64 * 64];
    __shared__ __attribute__((aligned(16))) _Float16 Ks[64 * 64];
    __shared__ __attribute__((aligned(16))) _Float16 Vs[128 * 64];
    __shared__ __attribute__((aligned(16))) _Float16 Ss[64 * 64];

    const _Float16* qg = qb + ((size_t)(b * S_ + n0) * H_ + hh) * DK_;
    const _Float16* kg = kb + ((size_t)(b * S_) * H_ + hh) * DK_;
    const _Float16* vg = Vt + (size_t)bh * DV_ * S_;

    #pragma unroll
    for (int c = 0; c < 2; c++) {                  // Q: 64 rows x 64 halves
        int chunk = c * 256 + t;
        int r = chunk >> 3, co = (chunk & 7) * 8;
        gl2lds16(qg + (size_t)r * (H_ * DK_) + co, Qs + chunk * 8);
    }
    double gd   = 1.0 - exp2((double)(-5 - hh));
    double l2gd = log2(gd);
    float  l2g  = (float)l2gd;
    float rn[4];
    #pragma unroll
    for (int r = 0; r < 4; r++) {
        int n = n0 + w * 16 + quad * 4 + r;
        double rowsum = (1.0 - exp2(l2gd * (double)(n + 1))) / (1.0 - gd);
        rn[r] = (float)(1.0 / sqrt(rowsum));
    }
    f32x4 oacc[8] = {};
    float absAcc[4] = {};

    for (int mt = 0; mt <= nt; mt++) {
        int m0 = mt * 64;
        __syncthreads();
        #pragma unroll
        for (int c = 0; c < 2; c++) {              // K tile: 64 x 64
            int chunk = c * 256 + t;
            int r = chunk >> 3, co = (chunk & 7) * 8;
            gl2lds16(kg + (size_t)(m0 + r) * (H_ * DK_) + co, Ks + chunk * 8);
        }
        #pragma unroll
        for (int c = 0; c < 4; c++) {              // V^T tile: 128 dv x 64 m
            int chunk = c * 256 + t;
            int dv = chunk >> 3, co = (chunk & 7) * 8;
            gl2lds16(vg + (size_t)dv * S_ + m0 + co, Vs + chunk * 8);
        }
        __syncthreads();
        // QK^T: wave w owns q rows w*16..+16
        f16x8 a0 = *(const f16x8*)&Qs[(w * 16 + l16) * 64 + quad * 8];
        f16x8 a1 = *(const f16x8*)&Qs[(w * 16 + l16) * 64 + 32 + quad * 8];
        f32x4 sacc[4] = {};
        #pragma unroll
        for (int j = 0; j < 4; j++) {
            f16x8 b0 = *(const f16x8*)&Ks[(j * 16 + l16) * 64 + quad * 8];
            f16x8 b1 = *(const f16x8*)&Ks[(j * 16 + l16) * 64 + 32 + quad * 8];
            sacc[j] = MFMA16(a0, b0, sacc[j]);
            sacc[j] = MFMA16(a1, b1, sacc[j]);
        }
        // decay mask + rnorm + |.| accumulation, write S (f16) for A-operand reuse
        #pragma unroll
        for (int j = 0; j < 4; j++) {
            int m = m0 + j * 16 + l16;
            #pragma unroll
            for (int r = 0; r < 4; r++) {
                int n = n0 + w * 16 + quad * 4 + r;
                float dm = (n >= m) ? exp2f((float)(n - m) * l2g) * rn[r] : 0.0f;
                float sv = sacc[j][r] * dm;
                absAcc[r] += fabsf(sv);
                Ss[(w * 16 + quad * 4 + r) * 64 + j * 16 + l16] = (_Float16)sv;
            }
        }
        __syncthreads();
        // S @ V
        f16x8 s0 = *(const f16x8*)&Ss[(w * 16 + l16) * 64 + quad * 8];
        f16x8 s1 = *(const f16x8*)&Ss[(w * 16 + l16) * 64 + 32 + quad * 8];
        #pragma unroll
        for (int j = 0; j < 8; j++) {
            f16x8 v0 = *(const f16x8*)&Vs[(j * 16 + l16) * 64 + quad * 8];
            f16x8 v1 = *(const f16x8*)&Vs[(j * 16 + l16) * 64 + 32 + quad * 8];
            oacc[j] = MFMA16(s0, v0, oacc[j]);
            oacc[j] = MFMA16(s1, v1, oacc[j]);
        }
    }
    // reduce row |S| sums across the 16 col-lanes
    #pragma unroll
    for (int r = 0; r < 4; r++) {
        float s_ = absAcc[r];
        #pragma unroll
        for (int off = 1; off < 16; off <<= 1) s_ += __shfl_xor(s_, off, 64);
        absAcc[r] = s_;
    }
    #pragma unroll
    for (int r = 0; r < 4; r++) {
        int n = n0 + w * 16 + quad * 4 + r;
        float sc = 1.0f / fmaxf(absAcc[r], 1.0f);
        float* og = of + ((size_t)(b * S_ + n) * H_ + hh) * DV_;
        #pragma unroll
        for (int j = 0; j < 8; j++)
            og[j * 16 + l16] = oacc[j][r] * sc;
    }
}

// ---------------------------------------------------------------- RMS over 128 + silu gate: fp32 o, f16 g -> f16
__global__ __launch_bounds__(256) void k_rmsgate(const float* __restrict__ o,
                                                 const _Float16* __restrict__ g,
                                                 _Float16* __restrict__ out) {
    size_t row = (size_t)blockIdx.x * 2 + (threadIdx.x >> 7);
    int tc = threadIdx.x & 127;
    size_t base = row * 128 + tc;
    float val = o[base];
    float gv  = (float)g[base];
    float ss = val * val;
    #pragma unroll
    for (int off = 32; off > 0; off >>= 1) ss += __shfl_down(ss, off, 64);
    __shared__ float sm[4];
    int wv = threadIdx.x >> 6;
    if ((threadIdx.x & 63) == 0) sm[wv] = ss;
    __syncthreads();
    int rw = (threadIdx.x >> 7) * 2;
    ss = sm[rw] + sm[rw + 1];
    float rms = 1.0f / sqrtf(ss * (1.0f / 128.0f) + 1e-6f);
    float sig = 1.0f / (1.0f + expf(-gv));
    out[base] = (_Float16)(gv * sig * val * rms);
}

// ---------------------------------------------------------------- final LN + logits (V=2) + log_softmax
__global__ __launch_bounds__(256) void k_final(const float* __restrict__ x,
                                               const float* __restrict__ s,
                                               const float* __restrict__ b,
                                               const float* __restrict__ Wout,
                                               float* __restrict__ out) {
    int row = blockIdx.x;
    int t = threadIdx.x;
    const float* xr = x + (size_t)row * D_;
    float4 xv = *(const float4*)&xr[t * 4];
    float sum = xv.x + xv.y + xv.z + xv.w;
    float ssq = xv.x * xv.x + xv.y * xv.y + xv.z * xv.z + xv.w * xv.w;
    __shared__ float sm1[4], sm2[4];
    #pragma unroll
    for (int off = 32; off > 0; off >>= 1) {
        sum += __shfl_down(sum, off, 64);
        ssq += __shfl_down(ssq, off, 64);
    }
    int lane = t & 63, w = t >> 6;
    if (lane == 0) { sm1[w] = sum; sm2[w] = ssq; }
    __syncthreads();
    sum = sm1[0] + sm1[1] + sm1[2] + sm1[3];
    ssq = sm2[0] + sm2[1] + sm2[2] + sm2[3];
    float mean = sum * (1.0f / D_);
    float var  = ssq * (1.0f / D_) - mean * mean;
    float inv  = 1.0f / sqrtf(var + 1e-5f);
    float4 sv = *(const float4*)&s[t * 4];
    float4 bv = *(const float4*)&b[t * 4];
    float ln[4];
    ln[0] = (xv.x - mean) * inv * sv.x + bv.x;
    ln[1] = (xv.y - mean) * inv * sv.y + bv.y;
    ln[2] = (xv.z - mean) * inv * sv.z + bv.z;
    ln[3] = (xv.w - mean) * inv * sv.w + bv.w;
    float l0 = 0.0f, l1 = 0.0f;
    #pragma unroll
    for (int i = 0; i < 4; i++) {
        int d = t * 4 + i;
        l0 += ln[i] * Wout[d * 2 + 0];
        l1 += ln[i] * Wout[d * 2 + 1];
    }
    #pragma unroll
    for (int off = 32; off > 0; off >>= 1) {
        l0 += __shfl_down(l0, off, 64);
        l1 += __shfl_down(l1, off, 64);
    }
    __syncthreads();
    if (lane == 0) { sm1[w] = l0; sm2[w] = l1; }
    __syncthreads();
    if (t == 0) {
        l0 = sm1[0] + sm1[1] + sm1[2] + sm1[3];
        l1 = sm2[0] + sm2[1] + sm2[2] + sm2[3];
        float mx  = fmaxf(l0, l1);
        float lse = mx + logf(expf(l0 - mx) + expf(l1 - mx));
        out[(size_t)row * 2 + 0] = l0 - lse;
        out[(size_t)row * 2 + 1] = l1 - lse;
    }
}

// ---------------------------------------------------------------- launch
extern "C" void kernel_launch(void* const* d_in, const int* in_sizes, int n_in,
                              void* d_out, int out_size, void* d_ws, size_t ws_size,
                              hipStream_t stream) {
    const int*   tokens = (const int*)d_in[0];
    const float* emb    = (const float*)d_in[1];
    const float* Wq     = (const float*)d_in[2];
    const float* Wk     = (const float*)d_in[3];
    const float* Wv     = (const float*)d_in[4];
    const float* Wg     = (const float*)d_in[5];
    const float* Wo     = (const float*)d_in[6];
    const float* ln1_s  = (const float*)d_in[7];
    const float* ln1_b  = (const float*)d_in[8];
    const float* ln2_s  = (const float*)d_in[9];
    const float* ln2_b  = (const float*)d_in[10];
    const float* W1     = (const float*)d_in[11];
    const float* b1     = (const float*)d_in[12];
    const float* W2     = (const float*)d_in[13];
    const float* b2     = (const float*)d_in[14];
    const float* lnf_s  = (const float*)d_in[15];
    const float* lnf_b  = (const float*)d_in[16];
    const float* Wout   = (const float*)d_in[17];

    float* ws = (float*)d_ws;
    const size_t M1 = 1u << 20;
    // layout in float units (total 38M floats = 152 MB):
    float*     h    = ws;                              // [0,4M) fp32
    _Float16*  x1h  = (_Float16*)(ws + 4 * M1);        // [4M,6M)  4M f16
    _Float16*  whb  = (_Float16*)(ws + 6 * M1);        // [6M,14M) 16M f16 weights
    _Float16*  wqT  = whb;                             // 1M
    _Float16*  wkT  = whb + 1 * M1;                    // 1M
    _Float16*  wvT  = whb + 2 * M1;                    // 2M
    _Float16*  wgT  = whb + 4 * M1;                    // 2M
    _Float16*  woT  = whb + 6 * M1;                    // 2M
    _Float16*  w1T  = whb + 8 * M1;                    // 4M
    _Float16*  w2T  = whb + 12 * M1;                   // 4M
    float*     qf   = ws + 14 * M1;                    // [14M,18M) fp32
    float*     kf   = ws + 18 * M1;                    // [18M,22M) fp32
    _Float16*  vh   = (_Float16*)(ws + 22 * M1);       // [22M,26M) 8M f16
    _Float16*  gh   = (_Float16*)(ws + 26 * M1);       // [26M,30M) 8M f16
    _Float16*  qh   = (_Float16*)(ws + 30 * M1);       // [30M,32M) 4M f16
    _Float16*  kh   = (_Float16*)(ws + 32 * M1);       // [32M,34M) 4M f16
    _Float16*  Vth  = (_Float16*)(ws + 34 * M1);       // [34M,38M) 8M f16
    float*     of   = ws + 14 * M1;                    // overlays qf/kf (dead after rope)
    _Float16*  oh   = (_Float16*)(ws + 22 * M1);       // overlays vh (dead after vtrans)
    _Float16*  f1h  = (_Float16*)(ws + 30 * M1);       // overlays qh/kh/Vth (dead after attn)

    k_embed<<<16384, 256, 0, stream>>>(tokens, emb, h);

    for (int l = 0; l < L_; l++) {
        const float* pWq = Wq + (size_t)l * M1;
        const float* pWk = Wk + (size_t)l * M1;
        const float* pWv = Wv + (size_t)l * 2 * M1;
        const float* pWg = Wg + (size_t)l * 2 * M1;
        const float* pWo = Wo + (size_t)l * 2 * M1;
        const float* pW1 = W1 + (size_t)l * 4 * M1;
        const float* pW2 = W2 + (size_t)l * 4 * M1;

        k_wcast<<<dim3(32, 32),  256, 0, stream>>>(pWq, wqT, 1024, 1024);
        k_wcast<<<dim3(32, 32),  256, 0, stream>>>(pWk, wkT, 1024, 1024);
        k_wcast<<<dim3(64, 32),  256, 0, stream>>>(pWv, wvT, 1024, 2048);
        k_wcast<<<dim3(64, 32),  256, 0, stream>>>(pWg, wgT, 1024, 2048);
        k_wcast<<<dim3(32, 64),  256, 0, stream>>>(pWo, woT, 2048, 1024);
        k_wcast<<<dim3(128, 32), 256, 0, stream>>>(pW1, w1T, 1024, 4096);
        k_wcast<<<dim3(32, 128), 256, 0, stream>>>(pW2, w2T, 4096, 1024);

        k_ln<<<4096, 256, 0, stream>>>(h, ln1_s + l * D_, ln1_b + l * D_, x1h);
        k_gemm_mfma<<<dim3(8, 32),  256, 0, stream>>>(x1h, wqT, nullptr, qf, nullptr, 4096, 1024, 1024, 0);
        k_gemm_mfma<<<dim3(8, 32),  256, 0, stream>>>(x1h, wkT, nullptr, kf, nullptr, 4096, 1024, 1024, 0);
        k_gemm_mfma<<<dim3(16, 32), 256, 0, stream>>>(x1h, wvT, nullptr, nullptr, vh, 4096, 2048, 1024, 8);
        k_gemm_mfma<<<dim3(16, 32), 256, 0, stream>>>(x1h, wgT, nullptr, nullptr, gh, 4096, 2048, 1024, 8);
        k_rope<<<8192, 256, 0, stream>>>(qf, qh, 1.0f);
        k_rope<<<8192, 256, 0, stream>>>(kf, kh, 0.125f);
        k_vtrans<<<dim3(16, 2, 64), 256, 0, stream>>>(vh, Vth);
        k_attn<<<dim3(16, 64), 256, 0, stream>>>(qh, kh, Vth, of);
        k_rmsgate<<<32768, 256, 0, stream>>>(of, gh, oh);
        k_gemm_mfma<<<dim3(8, 32),  256, 0, stream>>>(oh, woT, nullptr, h, nullptr, 4096, 1024, 2048, 1);
        k_ln<<<4096, 256, 0, stream>>>(h, ln2_s + l * D_, ln2_b + l * D_, x1h);
        k_gemm_mfma<<<dim3(32, 32), 256, 0, stream>>>(x1h, w1T, b1 + l * FFN_, nullptr, f1h, 4096, 4096, 1024, 2 | 4 | 8);
        k_gemm_mfma<<<dim3(8, 32),  256, 0, stream>>>(f1h, w2T, b2 + l * D_, h, nullptr, 4096, 1024, 4096, 1 | 2);
    }
    k_final<<<4096, 256, 0, stream>>>(h, lnf_s, lnf_b, Wout, (float*)d_out);
}

// Round 4
// 1583.519 us; speedup vs baseline: 6.4633x; 1.1841x over previous
//
#include <hip/hip_runtime.h>
#include <hip/hip_bf16.h>
#include <math.h>
#include <stdint.h>

#define D_   1024
#define H_   16
#define DK_  64
#define DV_  128
#define L_   3
#define FFN_ 4096
#define S_   1024
#define B_   4
#define NF_  6144   // fused QKVG output width

typedef __attribute__((ext_vector_type(8))) _Float16 f16x8;
typedef __attribute__((ext_vector_type(4))) _Float16 f16x4;
typedef __attribute__((ext_vector_type(4))) float f32x4;

__device__ __forceinline__ void gl2lds16(const void* g, void* l) {
    __builtin_amdgcn_global_load_lds(
        (const __attribute__((address_space(1))) void*)(uintptr_t)g,
        (__attribute__((address_space(3))) void*)(uintptr_t)l, 16, 0, 0);
}
#define MFMA16(a,b,c) __builtin_amdgcn_mfma_f32_16x16x32_f16(a,b,c,0,0,0)

// ---------------------------------------------------------------- embed (fp32 h)
__global__ __launch_bounds__(256) void k_embed(const int* __restrict__ tokens,
                                               const float* __restrict__ emb,
                                               float* __restrict__ h) {
    int i = blockIdx.x * 256 + threadIdx.x;
    int d  = i & (D_ - 1);
    int bs = i >> 10;
    int s  = bs & (S_ - 1);
    int b  = bs >> 10;
    int tok = (s == 0) ? 0 : tokens[b * S_ + s - 1];
    h[i] = emb[tok * D_ + d] * 32.0f;
}

// ---------------------------------------------------------------- layernorm -> fp16
__global__ __launch_bounds__(256) void k_ln(const float* __restrict__ x,
                                            const float* __restrict__ s,
                                            const float* __restrict__ b,
                                            _Float16* __restrict__ y) {
    int row = blockIdx.x;
    int t = threadIdx.x;
    const float* xr = x + (size_t)row * D_;
    float4 xv = *(const float4*)&xr[t * 4];
    float sum = xv.x + xv.y + xv.z + xv.w;
    float ssq = xv.x * xv.x + xv.y * xv.y + xv.z * xv.z + xv.w * xv.w;
    __shared__ float sm1[4], sm2[4];
    #pragma unroll
    for (int off = 32; off > 0; off >>= 1) {
        sum += __shfl_down(sum, off, 64);
        ssq += __shfl_down(ssq, off, 64);
    }
    int lane = t & 63, w = t >> 6;
    if (lane == 0) { sm1[w] = sum; sm2[w] = ssq; }
    __syncthreads();
    sum = sm1[0] + sm1[1] + sm1[2] + sm1[3];
    ssq = sm2[0] + sm2[1] + sm2[2] + sm2[3];
    float mean = sum * (1.0f / D_);
    float var  = ssq * (1.0f / D_) - mean * mean;
    float inv  = 1.0f / sqrtf(var + 1e-5f);
    float4 sv = *(const float4*)&s[t * 4];
    float4 bv = *(const float4*)&b[t * 4];
    f16x4 o;
    o.x = (_Float16)((xv.x - mean) * inv * sv.x + bv.x);
    o.y = (_Float16)((xv.y - mean) * inv * sv.y + bv.y);
    o.z = (_Float16)((xv.z - mean) * inv * sv.z + bv.z);
    o.w = (_Float16)((xv.w - mean) * inv * sv.w + bv.w);
    *(f16x4*)&y[(size_t)row * D_ + t * 4] = o;
}

// ---------------------------------------------------------------- weight cast+transpose: fp32 [K][N] -> fp16 [N][K]
__global__ __launch_bounds__(256) void k_wcast(const float* __restrict__ in,
                                               _Float16* __restrict__ out,
                                               int K, int N) {
    __shared__ float Ts[32][33];
    int n0 = blockIdx.x * 32, k0 = blockIdx.y * 32;
    int t = threadIdx.x;
    #pragma unroll
    for (int c = 0; c < 4; c++) {
        int e = c * 256 + t; int kr = e >> 5, nc = e & 31;
        Ts[kr][nc] = in[(size_t)(k0 + kr) * N + n0 + nc];
    }
    __syncthreads();
    #pragma unroll
    for (int c = 0; c < 4; c++) {
        int e = c * 256 + t; int nr = e >> 5, kc = e & 31;
        out[(size_t)(n0 + nr) * K + k0 + kc] = (_Float16)Ts[kc][nr];
    }
}

// ---------------------------------------------------------------- MFMA GEMM: C[M,N] = A[M,K](f16) @ Bt[N,K](f16)
// LDS tiles bank-swizzled: k-group cg stores global ko = (cg ^ ((row>>1)&3))*8.
// flags: 2=+bias, 4=gelu, 8=write f16 Ch; else write Cf fp32
__global__ __launch_bounds__(256) void k_gemm_mfma(
    const _Float16* __restrict__ A, const _Float16* __restrict__ Bt,
    const float* __restrict__ bias, float* __restrict__ Cf,
    _Float16* __restrict__ Ch, int M, int N, int K, int flags)
{
    __shared__ __attribute__((aligned(16))) _Float16 As[128 * 32];
    __shared__ __attribute__((aligned(16))) _Float16 Bs[128 * 32];
    int t = threadIdx.x;
    int n0 = blockIdx.x * 128, m0 = blockIdx.y * 128;
    int w = t >> 6, lane = t & 63;
    int quad = lane >> 4, l16 = lane & 15;
    int wm = (w >> 1) * 64, wn = (w & 1) * 64;
    // staging source mapping (swizzled)
    int srow = t >> 1;                       // covers 128 rows in 2 c-iters
    int scg0 = (t & 1) * 2;                  // cg pairs per thread? no: chunk math below
    (void)srow; (void)scg0;
    // hoisted swizzled fragment pointers
    const f16x8* aptr[4]; const f16x8* bptr[4];
    #pragma unroll
    for (int i = 0; i < 4; i++) {
        int ra = wm + i * 16 + l16;
        aptr[i] = (const f16x8*)&As[ra * 32 + ((quad ^ ((ra >> 1) & 3)) * 8)];
        int rb = wn + i * 16 + l16;
        bptr[i] = (const f16x8*)&Bs[rb * 32 + ((quad ^ ((rb >> 1) & 3)) * 8)];
    }
    f32x4 acc[4][4] = {};
    for (int k0 = 0; k0 < K; k0 += 32) {
        __syncthreads();
        #pragma unroll
        for (int c = 0; c < 2; c++) {
            int chunk = c * 256 + t;
            int row = chunk >> 2, cg = chunk & 3;
            int ko = (cg ^ ((row >> 1) & 3)) * 8;
            gl2lds16(A  + (size_t)(m0 + row) * K + k0 + ko, As + chunk * 8);
            gl2lds16(Bt + (size_t)(n0 + row) * K + k0 + ko, Bs + chunk * 8);
        }
        __syncthreads();
        f16x8 af[4], bfr[4];
        #pragma unroll
        for (int i = 0; i < 4; i++) af[i] = *aptr[i];
        #pragma unroll
        for (int j = 0; j < 4; j++) bfr[j] = *bptr[j];
        #pragma unroll
        for (int i = 0; i < 4; i++)
            #pragma unroll
            for (int j = 0; j < 4; j++)
                acc[i][j] = MFMA16(af[i], bfr[j], acc[i][j]);
    }
    #pragma unroll
    for (int i = 0; i < 4; i++) {
        #pragma unroll
        for (int r = 0; r < 4; r++) {
            int row = m0 + wm + i * 16 + quad * 4 + r;
            #pragma unroll
            for (int j = 0; j < 4; j++) {
                int col = n0 + wn + j * 16 + l16;
                float v = acc[i][j][r];
                if (flags & 2) v += bias[col];
                if (flags & 4) v = 0.5f * v * (1.0f + tanhf(0.7978845608f * (v + 0.044715f * v * v * v)));
                if (flags & 8) Ch[(size_t)row * N + col] = (_Float16)v;
                else Cf[(size_t)row * N + col] = v;
            }
        }
    }
}

// ---------------------------------------------------------------- split-K MFMA GEMM, atomicAdd into fp32 Cf
// grid.z = K / Kc chunks; bias added by chunk 0 only.
__global__ __launch_bounds__(256) void k_gemm_splitk(
    const _Float16* __restrict__ A, const _Float16* __restrict__ Bt,
    const float* __restrict__ bias, float* __restrict__ Cf,
    int M, int N, int K, int Kc)
{
    __shared__ __attribute__((aligned(16))) _Float16 As[128 * 32];
    __shared__ __attribute__((aligned(16))) _Float16 Bs[128 * 32];
    int t = threadIdx.x;
    int n0 = blockIdx.x * 128, m0 = blockIdx.y * 128;
    int kc = blockIdx.z;
    const _Float16* Ac  = A  + (size_t)kc * Kc;
    const _Float16* Btc = Bt + (size_t)kc * Kc;
    int w = t >> 6, lane = t & 63;
    int quad = lane >> 4, l16 = lane & 15;
    int wm = (w >> 1) * 64, wn = (w & 1) * 64;
    const f16x8* aptr[4]; const f16x8* bptr[4];
    #pragma unroll
    for (int i = 0; i < 4; i++) {
        int ra = wm + i * 16 + l16;
        aptr[i] = (const f16x8*)&As[ra * 32 + ((quad ^ ((ra >> 1) & 3)) * 8)];
        int rb = wn + i * 16 + l16;
        bptr[i] = (const f16x8*)&Bs[rb * 32 + ((quad ^ ((rb >> 1) & 3)) * 8)];
    }
    f32x4 acc[4][4] = {};
    for (int k0 = 0; k0 < Kc; k0 += 32) {
        __syncthreads();
        #pragma unroll
        for (int c = 0; c < 2; c++) {
            int chunk = c * 256 + t;
            int row = chunk >> 2, cg = chunk & 3;
            int ko = (cg ^ ((row >> 1) & 3)) * 8;
            gl2lds16(Ac  + (size_t)(m0 + row) * K + k0 + ko, As + chunk * 8);
            gl2lds16(Btc + (size_t)(n0 + row) * K + k0 + ko, Bs + chunk * 8);
        }
        __syncthreads();
        f16x8 af[4], bfr[4];
        #pragma unroll
        for (int i = 0; i < 4; i++) af[i] = *aptr[i];
        #pragma unroll
        for (int j = 0; j < 4; j++) bfr[j] = *bptr[j];
        #pragma unroll
        for (int i = 0; i < 4; i++)
            #pragma unroll
            for (int j = 0; j < 4; j++)
                acc[i][j] = MFMA16(af[i], bfr[j], acc[i][j]);
    }
    bool addb = (kc == 0) && (bias != nullptr);
    #pragma unroll
    for (int i = 0; i < 4; i++) {
        #pragma unroll
        for (int r = 0; r < 4; r++) {
            int row = m0 + wm + i * 16 + quad * 4 + r;
            #pragma unroll
            for (int j = 0; j < 4; j++) {
                int col = n0 + wn + j * 16 + l16;
                float v = acc[i][j][r];
                if (addb) v += bias[col];
                atomicAdd(&Cf[(size_t)row * N + col], v);
            }
        }
    }
}

// ---------------------------------------------------------------- RoPE in-place on f16 fused buffer (row stride NF_)
__global__ __launch_bounds__(256) void k_rope(_Float16* __restrict__ x, float scale) {
    int i = blockIdx.x * 256 + threadIdx.x;      // B*S*H*32 pair-threads
    int pair = i & 31;
    int hh = (i >> 5) & 15;
    int bs = i >> 9;
    int sIdx = bs & (S_ - 1);
    float ang = expf(-(float)pair * (1.0f / 31.0f) * 9.210340372f);
    float ph = (float)sIdx * ang;
    float sn, cs;
    sincosf(ph, &sn, &cs);
    size_t base = (size_t)bs * NF_ + hh * DK_ + 2 * pair;
    float x1 = (float)x[base], x2 = (float)x[base + 1];
    x[base]     = (_Float16)((x1 * cs - x2 * sn) * scale);
    x[base + 1] = (_Float16)((x2 * cs + x1 * sn) * scale);
}

// ---------------------------------------------------------------- V transpose: fused[.,2048+h*128+dv] -> [B][H][128][S]
__global__ __launch_bounds__(256) void k_vtrans(const _Float16* __restrict__ vb,
                                                _Float16* __restrict__ Vt) {
    int st = blockIdx.x, dt = blockIdx.y, bh = blockIdx.z;
    int hh = bh & 15, b = bh >> 4;
    __shared__ __attribute__((aligned(16))) _Float16 Ts[64][72];
    int t = threadIdx.x;
    const _Float16* src = vb + (size_t)(b * S_ + st * 64) * NF_ + 2048 + hh * DV_ + dt * 64;
    #pragma unroll
    for (int c = 0; c < 2; c++) {
        int chunk = c * 256 + t;
        int r = chunk >> 3, co = (chunk & 7) * 8;
        *(f16x8*)&Ts[r][co] = *(const f16x8*)(src + (size_t)r * NF_ + co);
    }
    __syncthreads();
    _Float16* dst = Vt + ((size_t)bh * DV_ + dt * 64) * S_ + st * 64;
    #pragma unroll
    for (int c = 0; c < 2; c++) {
        int chunk = c * 256 + t;
        int dr = chunk >> 3, so = (chunk & 7) * 8;
        f16x8 val;
        #pragma unroll
        for (int j = 0; j < 8; j++) val[j] = Ts[so + j][dr];
        *(f16x8*)(dst + (size_t)dr * S_ + so) = val;
    }
}

// ---------------------------------------------------------------- MFMA retention attention (bank-swizzled LDS)
// q,k from fused buffer (row stride NF_); Vt: [B][H][128][S] f16; o: fp32 [B][S][H*128]
__global__ __launch_bounds__(256) void k_attn(const _Float16* __restrict__ qkvg,
                                              const _Float16* __restrict__ Vt,
                                              float* __restrict__ of) {
    int nt = blockIdx.x, bh = blockIdx.y;
    int hh = bh & 15, b = bh >> 4;
    int t = threadIdx.x, w = t >> 6, lane = t & 63;
    int quad = lane >> 4, l16 = lane & 15;
    int n0 = nt * 64;

    __shared__ __attribute__((aligned(16))) _Float16 Qs[64 * 64];
    __shared__ __attribute__((aligned(16))) _Float16 Ks[64 * 64];
    __shared__ __attribute__((aligned(16))) _Float16 Vs[128 * 64];
    __shared__ __attribute__((aligned(16))) _Float16 Ss[64 * 64];

    const _Float16* qg = qkvg + (size_t)(b * S_ + n0) * NF_ + hh * DK_;          // q cols
    const _Float16* kg = qkvg + (size_t)(b * S_) * NF_ + 1024 + hh * DK_;        // k cols
    const _Float16* vg = Vt + (size_t)bh * DV_ * S_;

    // swizzled staging: chunk -> row=chunk>>3, cg=chunk&7, global ko=(cg^(row&7))*8
    #pragma unroll
    for (int c = 0; c < 2; c++) {
        int chunk = c * 256 + t;
        int r = chunk >> 3, cg = chunk & 7;
        int ko = (cg ^ (r & 7)) * 8;
        gl2lds16(qg + (size_t)r * NF_ + ko, Qs + chunk * 8);
    }
    double gd   = 1.0 - exp2((double)(-5 - hh));
    double l2gd = log2(gd);
    float  l2g  = (float)l2gd;
    float rn[4];
    #pragma unroll
    for (int r = 0; r < 4; r++) {
        int n = n0 + w * 16 + quad * 4 + r;
        double rowsum = (1.0 - exp2(l2gd * (double)(n + 1))) / (1.0 - gd);
        rn[r] = (float)(1.0 / sqrt(rowsum));
    }
    // hoisted swizzled fragment pointers
    int ra = w * 16 + l16;
    const f16x8* qp0 = (const f16x8*)&Qs[ra * 64 + (( quad      ^ (ra & 7)) * 8)];
    const f16x8* qp1 = (const f16x8*)&Qs[ra * 64 + (((quad + 4) ^ (ra & 7)) * 8)];
    const f16x8* sp0 = (const f16x8*)&Ss[ra * 64 + (( quad      ^ (ra & 7)) * 8)];
    const f16x8* sp1 = (const f16x8*)&Ss[ra * 64 + (((quad + 4) ^ (ra & 7)) * 8)];
    const f16x8* kp0[4]; const f16x8* kp1[4];
    const f16x8* vp0[8]; const f16x8* vp1[8];
    #pragma unroll
    for (int j = 0; j < 4; j++) {
        int rb = j * 16 + l16;
        kp0[j] = (const f16x8*)&Ks[rb * 64 + (( quad      ^ (rb & 7)) * 8)];
        kp1[j] = (const f16x8*)&Ks[rb * 64 + (((quad + 4) ^ (rb & 7)) * 8)];
    }
    #pragma unroll
    for (int j = 0; j < 8; j++) {
        int rv = j * 16 + l16;
        vp0[j] = (const f16x8*)&Vs[rv * 64 + (( quad      ^ (rv & 7)) * 8)];
        vp1[j] = (const f16x8*)&Vs[rv * 64 + (((quad + 4) ^ (rv & 7)) * 8)];
    }
    f32x4 oacc[8] = {};
    float absAcc[4] = {};

    for (int mt = 0; mt <= nt; mt++) {
        int m0 = mt * 64;
        __syncthreads();
        #pragma unroll
        for (int c = 0; c < 2; c++) {
            int chunk = c * 256 + t;
            int r = chunk >> 3, cg = chunk & 7;
            int ko = (cg ^ (r & 7)) * 8;
            gl2lds16(kg + (size_t)(m0 + r) * NF_ + ko, Ks + chunk * 8);
        }
        #pragma unroll
        for (int c = 0; c < 4; c++) {
            int chunk = c * 256 + t;
            int r = chunk >> 3, cg = chunk & 7;
            int ko = (cg ^ (r & 7)) * 8;
            gl2lds16(vg + (size_t)r * S_ + m0 + ko, Vs + chunk * 8);
        }
        __syncthreads();
        f16x8 a0 = *qp0, a1 = *qp1;
        f32x4 sacc[4] = {};
        #pragma unroll
        for (int j = 0; j < 4; j++) {
            sacc[j] = MFMA16(a0, *kp0[j], sacc[j]);
            sacc[j] = MFMA16(a1, *kp1[j], sacc[j]);
        }
        #pragma unroll
        for (int j = 0; j < 4; j++) {
            int m = m0 + j * 16 + l16;
            #pragma unroll
            for (int r = 0; r < 4; r++) {
                int n = n0 + w * 16 + quad * 4 + r;
                float dm = (n >= m) ? exp2f((float)(n - m) * l2g) * rn[r] : 0.0f;
                float sv = sacc[j][r] * dm;
                absAcc[r] += fabsf(sv);
                int rowS = w * 16 + quad * 4 + r;
                int colS = j * 16 + l16;
                Ss[rowS * 64 + ((((colS >> 3) ^ (rowS & 7)) << 3) | (colS & 7))] = (_Float16)sv;
            }
        }
        __syncthreads();
        f16x8 s0 = *sp0, s1 = *sp1;
        #pragma unroll
        for (int j = 0; j < 8; j++) {
            oacc[j] = MFMA16(s0, *vp0[j], oacc[j]);
            oacc[j] = MFMA16(s1, *vp1[j], oacc[j]);
        }
    }
    #pragma unroll
    for (int r = 0; r < 4; r++) {
        float s_ = absAcc[r];
        #pragma unroll
        for (int off = 1; off < 16; off <<= 1) s_ += __shfl_xor(s_, off, 64);
        absAcc[r] = s_;
    }
    #pragma unroll
    for (int r = 0; r < 4; r++) {
        int n = n0 + w * 16 + quad * 4 + r;
        float sc = 1.0f / fmaxf(absAcc[r], 1.0f);
        float* og = of + (size_t)(b * S_ + n) * (H_ * DV_) + hh * DV_;
        #pragma unroll
        for (int j = 0; j < 8; j++)
            og[j * 16 + l16] = oacc[j][r] * sc;
    }
}

// ---------------------------------------------------------------- RMS over 128 + silu gate: fp32 o, f16 g(fused) -> f16
__global__ __launch_bounds__(256) void k_rmsgate(const float* __restrict__ o,
                                                 const _Float16* __restrict__ qkvg,
                                                 _Float16* __restrict__ out) {
    int row = blockIdx.x * 2 + (threadIdx.x >> 7);   // row in [0, B*S*H)
    int tc = threadIdx.x & 127;
    int bs = row >> 4, hh = row & 15;
    size_t obase = (size_t)row * 128 + tc;
    float val = o[obase];
    float gv  = (float)qkvg[(size_t)bs * NF_ + 4096 + hh * DV_ + tc];
    float ss = val * val;
    #pragma unroll
    for (int off = 32; off > 0; off >>= 1) ss += __shfl_down(ss, off, 64);
    __shared__ float sm[4];
    int wv = threadIdx.x >> 6;
    if ((threadIdx.x & 63) == 0) sm[wv] = ss;
    __syncthreads();
    int rw = (threadIdx.x >> 7) * 2;
    ss = sm[rw] + sm[rw + 1];
    float rms = 1.0f / sqrtf(ss * (1.0f / 128.0f) + 1e-6f);
    float sig = 1.0f / (1.0f + expf(-gv));
    out[obase] = (_Float16)(gv * sig * val * rms);
}

// ---------------------------------------------------------------- final LN + logits (V=2) + log_softmax
__global__ __launch_bounds__(256) void k_final(const float* __restrict__ x,
                                               const float* __restrict__ s,
                                               const float* __restrict__ b,
                                               const float* __restrict__ Wout,
                                               float* __restrict__ out) {
    int row = blockIdx.x;
    int t = threadIdx.x;
    const float* xr = x + (size_t)row * D_;
    float4 xv = *(const float4*)&xr[t * 4];
    float sum = xv.x + xv.y + xv.z + xv.w;
    float ssq = xv.x * xv.x + xv.y * xv.y + xv.z * xv.z + xv.w * xv.w;
    __shared__ float sm1[4], sm2[4];
    #pragma unroll
    for (int off = 32; off > 0; off >>= 1) {
        sum += __shfl_down(sum, off, 64);
        ssq += __shfl_down(ssq, off, 64);
    }
    int lane = t & 63, w = t >> 6;
    if (lane == 0) { sm1[w] = sum; sm2[w] = ssq; }
    __syncthreads();
    sum = sm1[0] + sm1[1] + sm1[2] + sm1[3];
    ssq = sm2[0] + sm2[1] + sm2[2] + sm2[3];
    float mean = sum * (1.0f / D_);
    float var  = ssq * (1.0f / D_) - mean * mean;
    float inv  = 1.0f / sqrtf(var + 1e-5f);
    float4 sv = *(const float4*)&s[t * 4];
    float4 bv = *(const float4*)&b[t * 4];
    float ln[4];
    ln[0] = (xv.x - mean) * inv * sv.x + bv.x;
    ln[1] = (xv.y - mean) * inv * sv.y + bv.y;
    ln[2] = (xv.z - mean) * inv * sv.z + bv.z;
    ln[3] = (xv.w - mean) * inv * sv.w + bv.w;
    float l0 = 0.0f, l1 = 0.0f;
    #pragma unroll
    for (int i = 0; i < 4; i++) {
        int d = t * 4 + i;
        l0 += ln[i] * Wout[d * 2 + 0];
        l1 += ln[i] * Wout[d * 2 + 1];
    }
    #pragma unroll
    for (int off = 32; off > 0; off >>= 1) {
        l0 += __shfl_down(l0, off, 64);
        l1 += __shfl_down(l1, off, 64);
    }
    __syncthreads();
    if (lane == 0) { sm1[w] = l0; sm2[w] = l1; }
    __syncthreads();
    if (t == 0) {
        l0 = sm1[0] + sm1[1] + sm1[2] + sm1[3];
        l1 = sm2[0] + sm2[1] + sm2[2] + sm2[3];
        float mx  = fmaxf(l0, l1);
        float lse = mx + logf(expf(l0 - mx) + expf(l1 - mx));
        out[(size_t)row * 2 + 0] = l0 - lse;
        out[(size_t)row * 2 + 1] = l1 - lse;
    }
}

// ---------------------------------------------------------------- launch
extern "C" void kernel_launch(void* const* d_in, const int* in_sizes, int n_in,
                              void* d_out, int out_size, void* d_ws, size_t ws_size,
                              hipStream_t stream) {
    const int*   tokens = (const int*)d_in[0];
    const float* emb    = (const float*)d_in[1];
    const float* Wq     = (const float*)d_in[2];
    const float* Wk     = (const float*)d_in[3];
    const float* Wv     = (const float*)d_in[4];
    const float* Wg     = (const float*)d_in[5];
    const float* Wo     = (const float*)d_in[6];
    const float* ln1_s  = (const float*)d_in[7];
    const float* ln1_b  = (const float*)d_in[8];
    const float* ln2_s  = (const float*)d_in[9];
    const float* ln2_b  = (const float*)d_in[10];
    const float* W1     = (const float*)d_in[11];
    const float* b1     = (const float*)d_in[12];
    const float* W2     = (const float*)d_in[13];
    const float* b2     = (const float*)d_in[14];
    const float* lnf_s  = (const float*)d_in[15];
    const float* lnf_b  = (const float*)d_in[16];
    const float* Wout   = (const float*)d_in[17];

    float* ws = (float*)d_ws;
    const size_t M1 = 1u << 20;
    // layout in float units (total 39M floats = 156 MB):
    float*     h    = ws;                              // [0,4M) fp32
    _Float16*  x1h  = (_Float16*)(ws + 4 * M1);        // [4M,6M) 4M f16
    _Float16*  whb  = (_Float16*)(ws + 6 * M1);        // [6M,14M) 16M f16 weights
    _Float16*  wQKVG= whb;                             // [6144][1024] (q|k|v|g rows)
    _Float16*  woT  = whb + 6 * M1;                    // [1024][2048]
    _Float16*  w1T  = whb + 8 * M1;                    // [4096][1024]
    _Float16*  w2T  = whb + 12 * M1;                   // [1024][4096]
    _Float16*  qkvg = (_Float16*)(ws + 14 * M1);       // [14M,27M) [4096][6144] f16
    _Float16*  Vth  = (_Float16*)(ws + 27 * M1);       // [27M,31M) 8M f16
    float*     of   = ws + 31 * M1;                    // [31M,39M) fp32 [4096][2048]
    _Float16*  oh   = (_Float16*)(ws + 27 * M1);       // overlays Vth (dead after attn)
    _Float16*  f1h  = (_Float16*)(ws + 14 * M1);       // overlays qkvg (dead after rmsgate)

    k_embed<<<16384, 256, 0, stream>>>(tokens, emb, h);

    for (int l = 0; l < L_; l++) {
        const float* pWq = Wq + (size_t)l * M1;
        const float* pWk = Wk + (size_t)l * M1;
        const float* pWv = Wv + (size_t)l * 2 * M1;
        const float* pWg = Wg + (size_t)l * 2 * M1;
        const float* pWo = Wo + (size_t)l * 2 * M1;
        const float* pW1 = W1 + (size_t)l * 4 * M1;
        const float* pW2 = W2 + (size_t)l * 4 * M1;

        k_wcast<<<dim3(32, 32),  256, 0, stream>>>(pWq, wQKVG,          1024, 1024);
        k_wcast<<<dim3(32, 32),  256, 0, stream>>>(pWk, wQKVG + 1 * M1, 1024, 1024);
        k_wcast<<<dim3(64, 32),  256, 0, stream>>>(pWv, wQKVG + 2 * M1, 1024, 2048);
        k_wcast<<<dim3(64, 32),  256, 0, stream>>>(pWg, wQKVG + 4 * M1, 1024, 2048);
        k_wcast<<<dim3(32, 64),  256, 0, stream>>>(pWo, woT, 2048, 1024);
        k_wcast<<<dim3(128, 32), 256, 0, stream>>>(pW1, w1T, 1024, 4096);
        k_wcast<<<dim3(32, 128), 256, 0, stream>>>(pW2, w2T, 4096, 1024);

        k_ln<<<4096, 256, 0, stream>>>(h, ln1_s + l * D_, ln1_b + l * D_, x1h);
        // fused QKVG: [4096][6144] = x1h @ wQKVG^T
        k_gemm_mfma<<<dim3(48, 32), 256, 0, stream>>>(x1h, wQKVG, nullptr, nullptr, qkvg,
                                                      4096, NF_, 1024, 8);
        k_rope<<<8192, 256, 0, stream>>>(qkvg, 1.0f);            // q cols [0,1024)
        k_rope<<<8192, 256, 0, stream>>>(qkvg + 1024, 0.125f);   // k cols [1024,2048)
        k_vtrans<<<dim3(16, 2, 64), 256, 0, stream>>>(qkvg, Vth);
        k_attn<<<dim3(16, 64), 256, 0, stream>>>(qkvg, Vth, of);
        k_rmsgate<<<32768, 256, 0, stream>>>(of, qkvg, oh);
        // h += oh @ Wo  (split-K x2, atomic)
        k_gemm_splitk<<<dim3(8, 32, 2), 256, 0, stream>>>(oh, woT, nullptr, h,
                                                          4096, 1024, 2048, 1024);
        k_ln<<<4096, 256, 0, stream>>>(h, ln2_s + l * D_, ln2_b + l * D_, x1h);
        k_gemm_mfma<<<dim3(32, 32), 256, 0, stream>>>(x1h, w1T, b1 + l * FFN_, nullptr, f1h,
                                                      4096, 4096, 1024, 2 | 4 | 8);
        // h += f1h @ W2 + b2 (split-K x4, atomic)
        k_gemm_splitk<<<dim3(8, 32, 4), 256, 0, stream>>>(f1h, w2T, b2 + l * D_, h,
                                                          4096, 1024, 4096, 1024);
    }
    k_final<<<4096, 256, 0, stream>>>(h, lnf_s, lnf_b, Wout, (float*)d_out);
}

// Round 5
// 1477.752 us; speedup vs baseline: 6.9259x; 1.0716x over previous
//
#include <hip/hip_runtime.h>
#include <hip/hip_bf16.h>
#include <math.h>
#include <stdint.h>

#define D_   1024
#define H_   16
#define DK_  64
#define DV_  128
#define L_   3
#define FFN_ 4096
#define S_   1024
#define B_   4
#define NF_  6144   // fused QKVG output width

typedef __attribute__((ext_vector_type(8))) _Float16 f16x8;
typedef __attribute__((ext_vector_type(4))) _Float16 f16x4;
typedef __attribute__((ext_vector_type(4))) float f32x4;

__device__ __forceinline__ void gl2lds16(const void* g, void* l) {
    __builtin_amdgcn_global_load_lds(
        (const __attribute__((address_space(1))) void*)(uintptr_t)g,
        (__attribute__((address_space(3))) void*)(uintptr_t)l, 16, 0, 0);
}
#define MFMA16(a,b,c) __builtin_amdgcn_mfma_f32_16x16x32_f16(a,b,c,0,0,0)

// supertile swizzle: pid -> (m0, n0), 8x8 block groups for L2 locality.
// Requires (M/128)%8==0 and (N/128)%8==0.
__device__ __forceinline__ void tile_swizzle(int pid, int N, int* m0, int* n0) {
    int nb = N >> 7;
    int sgn = nb >> 3;                 // supertiles per n-row
    int sid = pid >> 6, wi = pid & 63;
    int smi = sid / sgn, sni = sid - smi * sgn;
    *m0 = ((smi << 3) + (wi >> 3)) << 7;
    *n0 = ((sni << 3) + (wi & 7)) << 7;
}

// ---------------------------------------------------------------- embed (fp32 h)
__global__ __launch_bounds__(256) void k_embed(const int* __restrict__ tokens,
                                               const float* __restrict__ emb,
                                               float* __restrict__ h) {
    int i = blockIdx.x * 256 + threadIdx.x;
    int d  = i & (D_ - 1);
    int bs = i >> 10;
    int s  = bs & (S_ - 1);
    int b  = bs >> 10;
    int tok = (s == 0) ? 0 : tokens[b * S_ + s - 1];
    h[i] = emb[tok * D_ + d] * 32.0f;
}

// ---------------------------------------------------------------- layernorm (+optional 2-partial reduce into x) -> fp16
__global__ __launch_bounds__(256) void k_ln(float* __restrict__ x,
                                            const float* __restrict__ p0,
                                            const float* __restrict__ p1,
                                            int np,
                                            const float* __restrict__ s,
                                            const float* __restrict__ b,
                                            _Float16* __restrict__ y) {
    int row = blockIdx.x;
    int t = threadIdx.x;
    size_t base = (size_t)row * D_ + t * 4;
    float4 xv = *(float4*)&x[base];
    if (np) {
        float4 a = *(const float4*)&p0[base];
        float4 c = *(const float4*)&p1[base];
        xv.x += a.x + c.x; xv.y += a.y + c.y;
        xv.z += a.z + c.z; xv.w += a.w + c.w;
        *(float4*)&x[base] = xv;           // h += partials (residual update)
    }
    float sum = xv.x + xv.y + xv.z + xv.w;
    float ssq = xv.x * xv.x + xv.y * xv.y + xv.z * xv.z + xv.w * xv.w;
    __shared__ float sm1[4], sm2[4];
    #pragma unroll
    for (int off = 32; off > 0; off >>= 1) {
        sum += __shfl_down(sum, off, 64);
        ssq += __shfl_down(ssq, off, 64);
    }
    int lane = t & 63, w = t >> 6;
    if (lane == 0) { sm1[w] = sum; sm2[w] = ssq; }
    __syncthreads();
    sum = sm1[0] + sm1[1] + sm1[2] + sm1[3];
    ssq = sm2[0] + sm2[1] + sm2[2] + sm2[3];
    float mean = sum * (1.0f / D_);
    float var  = ssq * (1.0f / D_) - mean * mean;
    float inv  = 1.0f / sqrtf(var + 1e-5f);
    float4 sv = *(const float4*)&s[t * 4];
    float4 bv = *(const float4*)&b[t * 4];
    f16x4 o;
    o.x = (_Float16)((xv.x - mean) * inv * sv.x + bv.x);
    o.y = (_Float16)((xv.y - mean) * inv * sv.y + bv.y);
    o.z = (_Float16)((xv.z - mean) * inv * sv.z + bv.z);
    o.w = (_Float16)((xv.w - mean) * inv * sv.w + bv.w);
    *(f16x4*)&y[base] = o;
}

// ---------------------------------------------------------------- weight cast+transpose: fp32 [K][N] -> fp16 [N][K]
__global__ __launch_bounds__(256) void k_wcast(const float* __restrict__ in,
                                               _Float16* __restrict__ out,
                                               int K, int N) {
    __shared__ float Ts[32][33];
    int n0 = blockIdx.x * 32, k0 = blockIdx.y * 32;
    int t = threadIdx.x;
    #pragma unroll
    for (int c = 0; c < 4; c++) {
        int e = c * 256 + t; int kr = e >> 5, nc = e & 31;
        Ts[kr][nc] = in[(size_t)(k0 + kr) * N + n0 + nc];
    }
    __syncthreads();
    #pragma unroll
    for (int c = 0; c < 4; c++) {
        int e = c * 256 + t; int nr = e >> 5, kc = e & 31;
        out[(size_t)(n0 + nr) * K + k0 + kc] = (_Float16)Ts[kc][nr];
    }
}

// ---------------------------------------------------------------- MFMA GEMM: C[M,N] = A[M,K](f16) @ Bt[N,K](f16)
// 1D grid (supertile-swizzled). flags: 2=+bias, 4=gelu, 8=write f16 Ch; else fp32 Cf
__global__ __launch_bounds__(256) void k_gemm_mfma(
    const _Float16* __restrict__ A, const _Float16* __restrict__ Bt,
    const float* __restrict__ bias, float* __restrict__ Cf,
    _Float16* __restrict__ Ch, int M, int N, int K, int flags)
{
    __shared__ __attribute__((aligned(16))) _Float16 As[128 * 32];
    __shared__ __attribute__((aligned(16))) _Float16 Bs[128 * 32];
    int t = threadIdx.x;
    int m0, n0;
    tile_swizzle(blockIdx.x, N, &m0, &n0);
    int w = t >> 6, lane = t & 63;
    int quad = lane >> 4, l16 = lane & 15;
    int wm = (w >> 1) * 64, wn = (w & 1) * 64;
    const f16x8* aptr[4]; const f16x8* bptr[4];
    #pragma unroll
    for (int i = 0; i < 4; i++) {
        int ra = wm + i * 16 + l16;
        aptr[i] = (const f16x8*)&As[ra * 32 + ((quad ^ ((ra >> 1) & 3)) * 8)];
        int rb = wn + i * 16 + l16;
        bptr[i] = (const f16x8*)&Bs[rb * 32 + ((quad ^ ((rb >> 1) & 3)) * 8)];
    }
    f32x4 acc[4][4] = {};
    for (int k0 = 0; k0 < K; k0 += 32) {
        __syncthreads();
        #pragma unroll
        for (int c = 0; c < 2; c++) {
            int chunk = c * 256 + t;
            int row = chunk >> 2, cg = chunk & 3;
            int ko = (cg ^ ((row >> 1) & 3)) * 8;
            gl2lds16(A  + (size_t)(m0 + row) * K + k0 + ko, As + chunk * 8);
            gl2lds16(Bt + (size_t)(n0 + row) * K + k0 + ko, Bs + chunk * 8);
        }
        __syncthreads();
        f16x8 af[4], bfr[4];
        #pragma unroll
        for (int i = 0; i < 4; i++) af[i] = *aptr[i];
        #pragma unroll
        for (int j = 0; j < 4; j++) bfr[j] = *bptr[j];
        #pragma unroll
        for (int i = 0; i < 4; i++)
            #pragma unroll
            for (int j = 0; j < 4; j++)
                acc[i][j] = MFMA16(af[i], bfr[j], acc[i][j]);
    }
    #pragma unroll
    for (int i = 0; i < 4; i++) {
        #pragma unroll
        for (int r = 0; r < 4; r++) {
            int row = m0 + wm + i * 16 + quad * 4 + r;
            #pragma unroll
            for (int j = 0; j < 4; j++) {
                int col = n0 + wn + j * 16 + l16;
                float v = acc[i][j][r];
                if (flags & 2) v += bias[col];
                if (flags & 4) v = 0.5f * v * (1.0f + tanhf(0.7978845608f * (v + 0.044715f * v * v * v)));
                if (flags & 8) Ch[(size_t)row * N + col] = (_Float16)v;
                else Cf[(size_t)row * N + col] = v;
            }
        }
    }
}

// ---------------------------------------------------------------- split-K MFMA GEMM -> partial buffers (no atomics)
// grid: (tiles, 1, z). Pz[z][M][N] fp32 plain stores; bias added by chunk 0 only.
__global__ __launch_bounds__(256) void k_gemm_splitk(
    const _Float16* __restrict__ A, const _Float16* __restrict__ Bt,
    const float* __restrict__ bias, float* __restrict__ P,
    int M, int N, int K, int Kc)
{
    __shared__ __attribute__((aligned(16))) _Float16 As[128 * 32];
    __shared__ __attribute__((aligned(16))) _Float16 Bs[128 * 32];
    int t = threadIdx.x;
    int m0, n0;
    tile_swizzle(blockIdx.x, N, &m0, &n0);
    int kc = blockIdx.z;
    const _Float16* Ac  = A  + (size_t)kc * Kc;
    const _Float16* Btc = Bt + (size_t)kc * Kc;
    float* Pz = P + (size_t)kc * M * N;
    int w = t >> 6, lane = t & 63;
    int quad = lane >> 4, l16 = lane & 15;
    int wm = (w >> 1) * 64, wn = (w & 1) * 64;
    const f16x8* aptr[4]; const f16x8* bptr[4];
    #pragma unroll
    for (int i = 0; i < 4; i++) {
        int ra = wm + i * 16 + l16;
        aptr[i] = (const f16x8*)&As[ra * 32 + ((quad ^ ((ra >> 1) & 3)) * 8)];
        int rb = wn + i * 16 + l16;
        bptr[i] = (const f16x8*)&Bs[rb * 32 + ((quad ^ ((rb >> 1) & 3)) * 8)];
    }
    f32x4 acc[4][4] = {};
    for (int k0 = 0; k0 < Kc; k0 += 32) {
        __syncthreads();
        #pragma unroll
        for (int c = 0; c < 2; c++) {
            int chunk = c * 256 + t;
            int row = chunk >> 2, cg = chunk & 3;
            int ko = (cg ^ ((row >> 1) & 3)) * 8;
            gl2lds16(Ac  + (size_t)(m0 + row) * K + k0 + ko, As + chunk * 8);
            gl2lds16(Btc + (size_t)(n0 + row) * K + k0 + ko, Bs + chunk * 8);
        }
        __syncthreads();
        f16x8 af[4], bfr[4];
        #pragma unroll
        for (int i = 0; i < 4; i++) af[i] = *aptr[i];
        #pragma unroll
        for (int j = 0; j < 4; j++) bfr[j] = *bptr[j];
        #pragma unroll
        for (int i = 0; i < 4; i++)
            #pragma unroll
            for (int j = 0; j < 4; j++)
                acc[i][j] = MFMA16(af[i], bfr[j], acc[i][j]);
    }
    bool addb = (kc == 0) && (bias != nullptr);
    #pragma unroll
    for (int i = 0; i < 4; i++) {
        #pragma unroll
        for (int r = 0; r < 4; r++) {
            int row = m0 + wm + i * 16 + quad * 4 + r;
            #pragma unroll
            for (int j = 0; j < 4; j++) {
                int col = n0 + wn + j * 16 + l16;
                float v = acc[i][j][r];
                if (addb) v += bias[col];
                Pz[(size_t)row * N + col] = v;
            }
        }
    }
}

// ---------------------------------------------------------------- RoPE in-place on f16 fused buffer (row stride NF_)
__global__ __launch_bounds__(256) void k_rope(_Float16* __restrict__ x, float scale) {
    int i = blockIdx.x * 256 + threadIdx.x;      // B*S*H*32 pair-threads
    int pair = i & 31;
    int hh = (i >> 5) & 15;
    int bs = i >> 9;
    int sIdx = bs & (S_ - 1);
    float ang = expf(-(float)pair * (1.0f / 31.0f) * 9.210340372f);
    float ph = (float)sIdx * ang;
    float sn, cs;
    sincosf(ph, &sn, &cs);
    size_t base = (size_t)bs * NF_ + hh * DK_ + 2 * pair;
    float x1 = (float)x[base], x2 = (float)x[base + 1];
    x[base]     = (_Float16)((x1 * cs - x2 * sn) * scale);
    x[base + 1] = (_Float16)((x2 * cs + x1 * sn) * scale);
}

// ---------------------------------------------------------------- V transpose: fused[.,2048+h*128+dv] -> [B][H][128][S]
__global__ __launch_bounds__(256) void k_vtrans(const _Float16* __restrict__ vb,
                                                _Float16* __restrict__ Vt) {
    int st = blockIdx.x, dt = blockIdx.y, bh = blockIdx.z;
    int hh = bh & 15, b = bh >> 4;
    __shared__ __attribute__((aligned(16))) _Float16 Ts[64][72];
    int t = threadIdx.x;
    const _Float16* src = vb + (size_t)(b * S_ + st * 64) * NF_ + 2048 + hh * DV_ + dt * 64;
    #pragma unroll
    for (int c = 0; c < 2; c++) {
        int chunk = c * 256 + t;
        int r = chunk >> 3, co = (chunk & 7) * 8;
        *(f16x8*)&Ts[r][co] = *(const f16x8*)(src + (size_t)r * NF_ + co);
    }
    __syncthreads();
    _Float16* dst = Vt + ((size_t)bh * DV_ + dt * 64) * S_ + st * 64;
    #pragma unroll
    for (int c = 0; c < 2; c++) {
        int chunk = c * 256 + t;
        int dr = chunk >> 3, so = (chunk & 7) * 8;
        f16x8 val;
        #pragma unroll
        for (int j = 0; j < 8; j++) val[j] = Ts[so + j][dr];
        *(f16x8*)(dst + (size_t)dr * S_ + so) = val;
    }
}

// ---------------------------------------------------------------- MFMA retention attention (bank-swizzled LDS)
__global__ __launch_bounds__(256) void k_attn(const _Float16* __restrict__ qkvg,
                                              const _Float16* __restrict__ Vt,
                                              float* __restrict__ of) {
    int nt = blockIdx.x, bh = blockIdx.y;
    int hh = bh & 15, b = bh >> 4;
    int t = threadIdx.x, w = t >> 6, lane = t & 63;
    int quad = lane >> 4, l16 = lane & 15;
    int n0 = nt * 64;

    __shared__ __attribute__((aligned(16))) _Float16 Qs[64 * 64];
    __shared__ __attribute__((aligned(16))) _Float16 Ks[64 * 64];
    __shared__ __attribute__((aligned(16))) _Float16 Vs[128 * 64];
    __shared__ __attribute__((aligned(16))) _Float16 Ss[64 * 64];

    const _Float16* qg = qkvg + (size_t)(b * S_ + n0) * NF_ + hh * DK_;
    const _Float16* kg = qkvg + (size_t)(b * S_) * NF_ + 1024 + hh * DK_;
    const _Float16* vg = Vt + (size_t)bh * DV_ * S_;

    #pragma unroll
    for (int c = 0; c < 2; c++) {
        int chunk = c * 256 + t;
        int r = chunk >> 3, cg = chunk & 7;
        int ko = (cg ^ (r & 7)) * 8;
        gl2lds16(qg + (size_t)r * NF_ + ko, Qs + chunk * 8);
    }
    double gd   = 1.0 - exp2((double)(-5 - hh));
    double l2gd = log2(gd);
    float  l2g  = (float)l2gd;
    float rn[4];
    #pragma unroll
    for (int r = 0; r < 4; r++) {
        int n = n0 + w * 16 + quad * 4 + r;
        double rowsum = (1.0 - exp2(l2gd * (double)(n + 1))) / (1.0 - gd);
        rn[r] = (float)(1.0 / sqrt(rowsum));
    }
    int ra = w * 16 + l16;
    const f16x8* qp0 = (const f16x8*)&Qs[ra * 64 + (( quad      ^ (ra & 7)) * 8)];
    const f16x8* qp1 = (const f16x8*)&Qs[ra * 64 + (((quad + 4) ^ (ra & 7)) * 8)];
    const f16x8* sp0 = (const f16x8*)&Ss[ra * 64 + (( quad      ^ (ra & 7)) * 8)];
    const f16x8* sp1 = (const f16x8*)&Ss[ra * 64 + (((quad + 4) ^ (ra & 7)) * 8)];
    const f16x8* kp0[4]; const f16x8* kp1[4];
    const f16x8* vp0[8]; const f16x8* vp1[8];
    #pragma unroll
    for (int j = 0; j < 4; j++) {
        int rb = j * 16 + l16;
        kp0[j] = (const f16x8*)&Ks[rb * 64 + (( quad      ^ (rb & 7)) * 8)];
        kp1[j] = (const f16x8*)&Ks[rb * 64 + (((quad + 4) ^ (rb & 7)) * 8)];
    }
    #pragma unroll
    for (int j = 0; j < 8; j++) {
        int rv = j * 16 + l16;
        vp0[j] = (const f16x8*)&Vs[rv * 64 + (( quad      ^ (rv & 7)) * 8)];
        vp1[j] = (const f16x8*)&Vs[rv * 64 + (((quad + 4) ^ (rv & 7)) * 8)];
    }
    f32x4 oacc[8] = {};
    float absAcc[4] = {};

    for (int mt = 0; mt <= nt; mt++) {
        int m0 = mt * 64;
        __syncthreads();
        #pragma unroll
        for (int c = 0; c < 2; c++) {
            int chunk = c * 256 + t;
            int r = chunk >> 3, cg = chunk & 7;
            int ko = (cg ^ (r & 7)) * 8;
            gl2lds16(kg + (size_t)(m0 + r) * NF_ + ko, Ks + chunk * 8);
        }
        #pragma unroll
        for (int c = 0; c < 4; c++) {
            int chunk = c * 256 + t;
            int r = chunk >> 3, cg = chunk & 7;
            int ko = (cg ^ (r & 7)) * 8;
            gl2lds16(vg + (size_t)r * S_ + m0 + ko, Vs + chunk * 8);
        }
        __syncthreads();
        f16x8 a0 = *qp0, a1 = *qp1;
        f32x4 sacc[4] = {};
        #pragma unroll
        for (int j = 0; j < 4; j++) {
            sacc[j] = MFMA16(a0, *kp0[j], sacc[j]);
            sacc[j] = MFMA16(a1, *kp1[j], sacc[j]);
        }
        #pragma unroll
        for (int j = 0; j < 4; j++) {
            int m = m0 + j * 16 + l16;
            #pragma unroll
            for (int r = 0; r < 4; r++) {
                int n = n0 + w * 16 + quad * 4 + r;
                float dm = (n >= m) ? exp2f((float)(n - m) * l2g) * rn[r] : 0.0f;
                float sv = sacc[j][r] * dm;
                absAcc[r] += fabsf(sv);
                int rowS = w * 16 + quad * 4 + r;
                int colS = j * 16 + l16;
                Ss[rowS * 64 + ((((colS >> 3) ^ (rowS & 7)) << 3) | (colS & 7))] = (_Float16)sv;
            }
        }
        __syncthreads();
        f16x8 s0 = *sp0, s1 = *sp1;
        #pragma unroll
        for (int j = 0; j < 8; j++) {
            oacc[j] = MFMA16(s0, *vp0[j], oacc[j]);
            oacc[j] = MFMA16(s1, *vp1[j], oacc[j]);
        }
    }
    #pragma unroll
    for (int r = 0; r < 4; r++) {
        float s_ = absAcc[r];
        #pragma unroll
        for (int off = 1; off < 16; off <<= 1) s_ += __shfl_xor(s_, off, 64);
        absAcc[r] = s_;
    }
    #pragma unroll
    for (int r = 0; r < 4; r++) {
        int n = n0 + w * 16 + quad * 4 + r;
        float sc = 1.0f / fmaxf(absAcc[r], 1.0f);
        float* og = of + (size_t)(b * S_ + n) * (H_ * DV_) + hh * DV_;
        #pragma unroll
        for (int j = 0; j < 8; j++)
            og[j * 16 + l16] = oacc[j][r] * sc;
    }
}

// ---------------------------------------------------------------- RMS over 128 + silu gate: fp32 o, f16 g(fused) -> f16
__global__ __launch_bounds__(256) void k_rmsgate(const float* __restrict__ o,
                                                 const _Float16* __restrict__ qkvg,
                                                 _Float16* __restrict__ out) {
    int row = blockIdx.x * 2 + (threadIdx.x >> 7);   // row in [0, B*S*H)
    int tc = threadIdx.x & 127;
    int bs = row >> 4, hh = row & 15;
    size_t obase = (size_t)row * 128 + tc;
    float val = o[obase];
    float gv  = (float)qkvg[(size_t)bs * NF_ + 4096 + hh * DV_ + tc];
    float ss = val * val;
    #pragma unroll
    for (int off = 32; off > 0; off >>= 1) ss += __shfl_down(ss, off, 64);
    __shared__ float sm[4];
    int wv = threadIdx.x >> 6;
    if ((threadIdx.x & 63) == 0) sm[wv] = ss;
    __syncthreads();
    int rw = (threadIdx.x >> 7) * 2;
    ss = sm[rw] + sm[rw + 1];
    float rms = 1.0f / sqrtf(ss * (1.0f / 128.0f) + 1e-6f);
    float sig = 1.0f / (1.0f + expf(-gv));
    out[obase] = (_Float16)(gv * sig * val * rms);
}

// ---------------------------------------------------------------- final: 2-partial reduce + LN + logits (V=2) + log_softmax
__global__ __launch_bounds__(256) void k_final(const float* __restrict__ x,
                                               const float* __restrict__ p0,
                                               const float* __restrict__ p1,
                                               const float* __restrict__ s,
                                               const float* __restrict__ b,
                                               const float* __restrict__ Wout,
                                               float* __restrict__ out) {
    int row = blockIdx.x;
    int t = threadIdx.x;
    size_t base = (size_t)row * D_ + t * 4;
    float4 xv = *(const float4*)&x[base];
    {
        float4 a = *(const float4*)&p0[base];
        float4 c = *(const float4*)&p1[base];
        xv.x += a.x + c.x; xv.y += a.y + c.y;
        xv.z += a.z + c.z; xv.w += a.w + c.w;
    }
    float sum = xv.x + xv.y + xv.z + xv.w;
    float ssq = xv.x * xv.x + xv.y * xv.y + xv.z * xv.z + xv.w * xv.w;
    __shared__ float sm1[4], sm2[4];
    #pragma unroll
    for (int off = 32; off > 0; off >>= 1) {
        sum += __shfl_down(sum, off, 64);
        ssq += __shfl_down(ssq, off, 64);
    }
    int lane = t & 63, w = t >> 6;
    if (lane == 0) { sm1[w] = sum; sm2[w] = ssq; }
    __syncthreads();
    sum = sm1[0] + sm1[1] + sm1[2] + sm1[3];
    ssq = sm2[0] + sm2[1] + sm2[2] + sm2[3];
    float mean = sum * (1.0f / D_);
    float var  = ssq * (1.0f / D_) - mean * mean;
    float inv  = 1.0f / sqrtf(var + 1e-5f);
    float4 sv = *(const float4*)&s[t * 4];
    float4 bv = *(const float4*)&b[t * 4];
    float ln[4];
    ln[0] = (xv.x - mean) * inv * sv.x + bv.x;
    ln[1] = (xv.y - mean) * inv * sv.y + bv.y;
    ln[2] = (xv.z - mean) * inv * sv.z + bv.z;
    ln[3] = (xv.w - mean) * inv * sv.w + bv.w;
    float l0 = 0.0f, l1 = 0.0f;
    #pragma unroll
    for (int i = 0; i < 4; i++) {
        int d = t * 4 + i;
        l0 += ln[i] * Wout[d * 2 + 0];
        l1 += ln[i] * Wout[d * 2 + 1];
    }
    #pragma unroll
    for (int off = 32; off > 0; off >>= 1) {
        l0 += __shfl_down(l0, off, 64);
        l1 += __shfl_down(l1, off, 64);
    }
    __syncthreads();
    if (lane == 0) { sm1[w] = l0; sm2[w] = l1; }
    __syncthreads();
    if (t == 0) {
        l0 = sm1[0] + sm1[1] + sm1[2] + sm1[3];
        l1 = sm2[0] + sm2[1] + sm2[2] + sm2[3];
        float mx  = fmaxf(l0, l1);
        float lse = mx + logf(expf(l0 - mx) + expf(l1 - mx));
        out[(size_t)row * 2 + 0] = l0 - lse;
        out[(size_t)row * 2 + 1] = l1 - lse;
    }
}

// ---------------------------------------------------------------- launch
extern "C" void kernel_launch(void* const* d_in, const int* in_sizes, int n_in,
                              void* d_out, int out_size, void* d_ws, size_t ws_size,
                              hipStream_t stream) {
    const int*   tokens = (const int*)d_in[0];
    const float* emb    = (const float*)d_in[1];
    const float* Wq     = (const float*)d_in[2];
    const float* Wk     = (const float*)d_in[3];
    const float* Wv     = (const float*)d_in[4];
    const float* Wg     = (const float*)d_in[5];
    const float* Wo     = (const float*)d_in[6];
    const float* ln1_s  = (const float*)d_in[7];
    const float* ln1_b  = (const float*)d_in[8];
    const float* ln2_s  = (const float*)d_in[9];
    const float* ln2_b  = (const float*)d_in[10];
    const float* W1     = (const float*)d_in[11];
    const float* b1     = (const float*)d_in[12];
    const float* W2     = (const float*)d_in[13];
    const float* b2     = (const float*)d_in[14];
    const float* lnf_s  = (const float*)d_in[15];
    const float* lnf_b  = (const float*)d_in[16];
    const float* Wout   = (const float*)d_in[17];

    float* ws = (float*)d_ws;
    const size_t M1 = 1u << 20;
    // layout in float units (total 39M floats = 156 MB):
    float*     h    = ws;                              // [0,4M) fp32
    _Float16*  x1h  = (_Float16*)(ws + 4 * M1);        // [4M,6M) 4M f16
    _Float16*  whb  = (_Float16*)(ws + 6 * M1);        // [6M,14M) 16M f16 weights
    _Float16*  wQKVG= whb;                             // [6144][1024]
    _Float16*  woT  = whb + 6 * M1;                    // [1024][2048]
    _Float16*  w1T  = whb + 8 * M1;                    // [4096][1024]
    _Float16*  w2T  = whb + 12 * M1;                   // [1024][4096]
    _Float16*  qkvg = (_Float16*)(ws + 14 * M1);       // [14M,27M) [4096][6144] f16
    _Float16*  Vth  = (_Float16*)(ws + 27 * M1);       // [27M,31M) 8M f16
    float*     of   = ws + 31 * M1;                    // [31M,39M) fp32 [4096][2048]
    _Float16*  oh   = (_Float16*)(ws + 27 * M1);       // overlays Vth (dead after attn)
    _Float16*  f1h  = (_Float16*)(ws + 14 * M1);       // overlays qkvg (dead after rmsgate)
    float*     pb0  = ws + 31 * M1;                    // partials overlay `of` (dead after rmsgate)
    float*     pb1  = ws + 35 * M1;

    k_embed<<<16384, 256, 0, stream>>>(tokens, emb, h);

    for (int l = 0; l < L_; l++) {
        const float* pWq = Wq + (size_t)l * M1;
        const float* pWk = Wk + (size_t)l * M1;
        const float* pWv = Wv + (size_t)l * 2 * M1;
        const float* pWg = Wg + (size_t)l * 2 * M1;
        const float* pWo = Wo + (size_t)l * 2 * M1;
        const float* pW1 = W1 + (size_t)l * 4 * M1;
        const float* pW2 = W2 + (size_t)l * 4 * M1;

        k_wcast<<<dim3(32, 32),  256, 0, stream>>>(pWq, wQKVG,          1024, 1024);
        k_wcast<<<dim3(32, 32),  256, 0, stream>>>(pWk, wQKVG + 1 * M1, 1024, 1024);
        k_wcast<<<dim3(64, 32),  256, 0, stream>>>(pWv, wQKVG + 2 * M1, 1024, 2048);
        k_wcast<<<dim3(64, 32),  256, 0, stream>>>(pWg, wQKVG + 4 * M1, 1024, 2048);
        k_wcast<<<dim3(32, 64),  256, 0, stream>>>(pWo, woT, 2048, 1024);
        k_wcast<<<dim3(128, 32), 256, 0, stream>>>(pW1, w1T, 1024, 4096);
        k_wcast<<<dim3(32, 128), 256, 0, stream>>>(pW2, w2T, 4096, 1024);

        // ln1: layer 0 has no pending partials; layers 1,2 fold in prev layer's W2 partials
        k_ln<<<4096, 256, 0, stream>>>(h, pb0, pb1, (l == 0) ? 0 : 1,
                                       ln1_s + l * D_, ln1_b + l * D_, x1h);
        // fused QKVG: [4096][6144] = x1h @ wQKVG^T   (48*32 = 1536 tiles)
        k_gemm_mfma<<<dim3(1536), 256, 0, stream>>>(x1h, wQKVG, nullptr, nullptr, qkvg,
                                                    4096, NF_, 1024, 8);
        k_rope<<<8192, 256, 0, stream>>>(qkvg, 1.0f);            // q cols [0,1024)
        k_rope<<<8192, 256, 0, stream>>>(qkvg + 1024, 0.125f);   // k cols [1024,2048)
        k_vtrans<<<dim3(16, 2, 64), 256, 0, stream>>>(qkvg, Vth);
        k_attn<<<dim3(16, 64), 256, 0, stream>>>(qkvg, Vth, of);
        k_rmsgate<<<32768, 256, 0, stream>>>(of, qkvg, oh);
        // Wo partials (split-K x2, Kc=1024): pb[z] = oh @ woT_chunk
        k_gemm_splitk<<<dim3(256, 1, 2), 256, 0, stream>>>(oh, woT, nullptr, pb0,
                                                           4096, 1024, 2048, 1024);
        // ln2 folds Wo partials into h
        k_ln<<<4096, 256, 0, stream>>>(h, pb0, pb1, 1,
                                       ln2_s + l * D_, ln2_b + l * D_, x1h);
        k_gemm_mfma<<<dim3(1024), 256, 0, stream>>>(x1h, w1T, b1 + l * FFN_, nullptr, f1h,
                                                    4096, 4096, 1024, 2 | 4 | 8);
        // W2 partials (split-K x2, Kc=2048): folded by next ln1 or k_final
        k_gemm_splitk<<<dim3(256, 1, 2), 256, 0, stream>>>(f1h, w2T, b2 + l * D_, pb0,
                                                           4096, 1024, 4096, 2048);
    }
    k_final<<<4096, 256, 0, stream>>>(h, pb0, pb1, lnf_s, lnf_b, Wout, (float*)d_out);
}

// Round 6
// 1459.112 us; speedup vs baseline: 7.0144x; 1.0128x over previous
//
#include <hip/hip_runtime.h>
#include <hip/hip_bf16.h>
#include <math.h>
#include <stdint.h>

#define D_   1024
#define H_   16
#define DK_  64
#define DV_  128
#define L_   3
#define FFN_ 4096
#define S_   1024
#define B_   4
#define NF_  6144   // fused QKVG output width

typedef __attribute__((ext_vector_type(8))) _Float16 f16x8;
typedef __attribute__((ext_vector_type(4))) _Float16 f16x4;
typedef __attribute__((ext_vector_type(4))) float f32x4;

__device__ __forceinline__ void gl2lds16(const void* g, void* l) {
    __builtin_amdgcn_global_load_lds(
        (const __attribute__((address_space(1))) void*)(uintptr_t)g,
        (__attribute__((address_space(3))) void*)(uintptr_t)l, 16, 0, 0);
}
#define MFMA16(a,b,c) __builtin_amdgcn_mfma_f32_16x16x32_f16(a,b,c,0,0,0)

// fast gelu (tanh-approx, sigmoid form): 0.5v(1+tanh(y)) == v*sigmoid(2y), hw v_exp
__device__ __forceinline__ float fast_gelu(float v) {
    float y = 1.5957691216f * (v + 0.044715f * v * v * v);
    return v * (1.0f / (1.0f + __expf(-y)));
}

// supertile swizzle: pid -> (m0, n0), 8x8 block groups for L2 locality.
// Requires (M/128)%8==0 and (N/128)%8==0.
__device__ __forceinline__ void tile_swizzle(int pid, int N, int* m0, int* n0) {
    int nb = N >> 7;
    int sgn = nb >> 3;                 // supertiles per n-row
    int sid = pid >> 6, wi = pid & 63;
    int smi = sid / sgn, sni = sid - smi * sgn;
    *m0 = ((smi << 3) + (wi >> 3)) << 7;
    *n0 = ((sni << 3) + (wi & 7)) << 7;
}

// ---------------------------------------------------------------- embed (fp32 h)
__global__ __launch_bounds__(256) void k_embed(const int* __restrict__ tokens,
                                               const float* __restrict__ emb,
                                               float* __restrict__ h) {
    int i = blockIdx.x * 256 + threadIdx.x;
    int d  = i & (D_ - 1);
    int bs = i >> 10;
    int s  = bs & (S_ - 1);
    int b  = bs >> 10;
    int tok = (s == 0) ? 0 : tokens[b * S_ + s - 1];
    h[i] = emb[tok * D_ + d] * 32.0f;
}

// ---------------------------------------------------------------- layernorm (+optional 2-partial reduce into x) -> fp16
__global__ __launch_bounds__(256) void k_ln(float* __restrict__ x,
                                            const float* __restrict__ p0,
                                            const float* __restrict__ p1,
                                            int np,
                                            const float* __restrict__ s,
                                            const float* __restrict__ b,
                                            _Float16* __restrict__ y) {
    int row = blockIdx.x;
    int t = threadIdx.x;
    size_t base = (size_t)row * D_ + t * 4;
    float4 xv = *(float4*)&x[base];
    if (np) {
        float4 a = *(const float4*)&p0[base];
        float4 c = *(const float4*)&p1[base];
        xv.x += a.x + c.x; xv.y += a.y + c.y;
        xv.z += a.z + c.z; xv.w += a.w + c.w;
        *(float4*)&x[base] = xv;           // h += partials (residual update)
    }
    float sum = xv.x + xv.y + xv.z + xv.w;
    float ssq = xv.x * xv.x + xv.y * xv.y + xv.z * xv.z + xv.w * xv.w;
    __shared__ float sm1[4], sm2[4];
    #pragma unroll
    for (int off = 32; off > 0; off >>= 1) {
        sum += __shfl_down(sum, off, 64);
        ssq += __shfl_down(ssq, off, 64);
    }
    int lane = t & 63, w = t >> 6;
    if (lane == 0) { sm1[w] = sum; sm2[w] = ssq; }
    __syncthreads();
    sum = sm1[0] + sm1[1] + sm1[2] + sm1[3];
    ssq = sm2[0] + sm2[1] + sm2[2] + sm2[3];
    float mean = sum * (1.0f / D_);
    float var  = ssq * (1.0f / D_) - mean * mean;
    float inv  = 1.0f / sqrtf(var + 1e-5f);
    float4 sv = *(const float4*)&s[t * 4];
    float4 bv = *(const float4*)&b[t * 4];
    f16x4 o;
    o.x = (_Float16)((xv.x - mean) * inv * sv.x + bv.x);
    o.y = (_Float16)((xv.y - mean) * inv * sv.y + bv.y);
    o.z = (_Float16)((xv.z - mean) * inv * sv.z + bv.z);
    o.w = (_Float16)((xv.w - mean) * inv * sv.w + bv.w);
    *(f16x4*)&y[base] = o;
}

// ---------------------------------------------------------------- weight cast+transpose: fp32 [K][N] -> fp16 [N][K]
__global__ __launch_bounds__(256) void k_wcast(const float* __restrict__ in,
                                               _Float16* __restrict__ out,
                                               int K, int N) {
    __shared__ float Ts[32][33];
    int n0 = blockIdx.x * 32, k0 = blockIdx.y * 32;
    int t = threadIdx.x;
    #pragma unroll
    for (int c = 0; c < 4; c++) {
        int e = c * 256 + t; int kr = e >> 5, nc = e & 31;
        Ts[kr][nc] = in[(size_t)(k0 + kr) * N + n0 + nc];
    }
    __syncthreads();
    #pragma unroll
    for (int c = 0; c < 4; c++) {
        int e = c * 256 + t; int nr = e >> 5, kc = e & 31;
        out[(size_t)(n0 + nr) * K + k0 + kc] = (_Float16)Ts[kc][nr];
    }
}

// ---------------------------------------------------------------- MFMA GEMM: C[M,N] = A[M,K](f16) @ Bt[N,K](f16)
// 1D grid (supertile-swizzled). flags: 2=+bias, 4=gelu, 8=write f16 Ch; else fp32 Cf
__global__ __launch_bounds__(256) void k_gemm_mfma(
    const _Float16* __restrict__ A, const _Float16* __restrict__ Bt,
    const float* __restrict__ bias, float* __restrict__ Cf,
    _Float16* __restrict__ Ch, int M, int N, int K, int flags)
{
    __shared__ __attribute__((aligned(16))) _Float16 As[128 * 32];
    __shared__ __attribute__((aligned(16))) _Float16 Bs[128 * 32];
    int t = threadIdx.x;
    int m0, n0;
    tile_swizzle(blockIdx.x, N, &m0, &n0);
    int w = t >> 6, lane = t & 63;
    int quad = lane >> 4, l16 = lane & 15;
    int wm = (w >> 1) * 64, wn = (w & 1) * 64;
    const f16x8* aptr[4]; const f16x8* bptr[4];
    #pragma unroll
    for (int i = 0; i < 4; i++) {
        int ra = wm + i * 16 + l16;
        aptr[i] = (const f16x8*)&As[ra * 32 + ((quad ^ ((ra >> 1) & 3)) * 8)];
        int rb = wn + i * 16 + l16;
        bptr[i] = (const f16x8*)&Bs[rb * 32 + ((quad ^ ((rb >> 1) & 3)) * 8)];
    }
    f32x4 acc[4][4] = {};
    for (int k0 = 0; k0 < K; k0 += 32) {
        __syncthreads();
        #pragma unroll
        for (int c = 0; c < 2; c++) {
            int chunk = c * 256 + t;
            int row = chunk >> 2, cg = chunk & 3;
            int ko = (cg ^ ((row >> 1) & 3)) * 8;
            gl2lds16(A  + (size_t)(m0 + row) * K + k0 + ko, As + chunk * 8);
            gl2lds16(Bt + (size_t)(n0 + row) * K + k0 + ko, Bs + chunk * 8);
        }
        __syncthreads();
        f16x8 af[4], bfr[4];
        #pragma unroll
        for (int i = 0; i < 4; i++) af[i] = *aptr[i];
        #pragma unroll
        for (int j = 0; j < 4; j++) bfr[j] = *bptr[j];
        #pragma unroll
        for (int i = 0; i < 4; i++)
            #pragma unroll
            for (int j = 0; j < 4; j++)
                acc[i][j] = MFMA16(af[i], bfr[j], acc[i][j]);
    }
    #pragma unroll
    for (int i = 0; i < 4; i++) {
        #pragma unroll
        for (int r = 0; r < 4; r++) {
            int row = m0 + wm + i * 16 + quad * 4 + r;
            #pragma unroll
            for (int j = 0; j < 4; j++) {
                int col = n0 + wn + j * 16 + l16;
                float v = acc[i][j][r];
                if (flags & 2) v += bias[col];
                if (flags & 4) v = fast_gelu(v);
                if (flags & 8) Ch[(size_t)row * N + col] = (_Float16)v;
                else Cf[(size_t)row * N + col] = v;
            }
        }
    }
}

// ---------------------------------------------------------------- split-K MFMA GEMM -> partial buffers (no atomics)
// grid: (tiles, 1, z). Pz[z][M][N] fp32 plain stores; bias added by chunk 0 only.
__global__ __launch_bounds__(256) void k_gemm_splitk(
    const _Float16* __restrict__ A, const _Float16* __restrict__ Bt,
    const float* __restrict__ bias, float* __restrict__ P,
    int M, int N, int K, int Kc)
{
    __shared__ __attribute__((aligned(16))) _Float16 As[128 * 32];
    __shared__ __attribute__((aligned(16))) _Float16 Bs[128 * 32];
    int t = threadIdx.x;
    int m0, n0;
    tile_swizzle(blockIdx.x, N, &m0, &n0);
    int kc = blockIdx.z;
    const _Float16* Ac  = A  + (size_t)kc * Kc;
    const _Float16* Btc = Bt + (size_t)kc * Kc;
    float* Pz = P + (size_t)kc * M * N;
    int w = t >> 6, lane = t & 63;
    int quad = lane >> 4, l16 = lane & 15;
    int wm = (w >> 1) * 64, wn = (w & 1) * 64;
    const f16x8* aptr[4]; const f16x8* bptr[4];
    #pragma unroll
    for (int i = 0; i < 4; i++) {
        int ra = wm + i * 16 + l16;
        aptr[i] = (const f16x8*)&As[ra * 32 + ((quad ^ ((ra >> 1) & 3)) * 8)];
        int rb = wn + i * 16 + l16;
        bptr[i] = (const f16x8*)&Bs[rb * 32 + ((quad ^ ((rb >> 1) & 3)) * 8)];
    }
    f32x4 acc[4][4] = {};
    for (int k0 = 0; k0 < Kc; k0 += 32) {
        __syncthreads();
        #pragma unroll
        for (int c = 0; c < 2; c++) {
            int chunk = c * 256 + t;
            int row = chunk >> 2, cg = chunk & 3;
            int ko = (cg ^ ((row >> 1) & 3)) * 8;
            gl2lds16(Ac  + (size_t)(m0 + row) * K + k0 + ko, As + chunk * 8);
            gl2lds16(Btc + (size_t)(n0 + row) * K + k0 + ko, Bs + chunk * 8);
        }
        __syncthreads();
        f16x8 af[4], bfr[4];
        #pragma unroll
        for (int i = 0; i < 4; i++) af[i] = *aptr[i];
        #pragma unroll
        for (int j = 0; j < 4; j++) bfr[j] = *bptr[j];
        #pragma unroll
        for (int i = 0; i < 4; i++)
            #pragma unroll
            for (int j = 0; j < 4; j++)
                acc[i][j] = MFMA16(af[i], bfr[j], acc[i][j]);
    }
    bool addb = (kc == 0) && (bias != nullptr);
    #pragma unroll
    for (int i = 0; i < 4; i++) {
        #pragma unroll
        for (int r = 0; r < 4; r++) {
            int row = m0 + wm + i * 16 + quad * 4 + r;
            #pragma unroll
            for (int j = 0; j < 4; j++) {
                int col = n0 + wn + j * 16 + l16;
                float v = acc[i][j][r];
                if (addb) v += bias[col];
                Pz[(size_t)row * N + col] = v;
            }
        }
    }
}

// ---------------------------------------------------------------- RoPE in-place on f16 fused buffer (row stride NF_)
__global__ __launch_bounds__(256) void k_rope(_Float16* __restrict__ x, float scale) {
    int i = blockIdx.x * 256 + threadIdx.x;      // B*S*H*32 pair-threads
    int pair = i & 31;
    int hh = (i >> 5) & 15;
    int bs = i >> 9;
    int sIdx = bs & (S_ - 1);
    float ang = expf(-(float)pair * (1.0f / 31.0f) * 9.210340372f);
    float ph = (float)sIdx * ang;
    float sn, cs;
    sincosf(ph, &sn, &cs);
    size_t base = (size_t)bs * NF_ + hh * DK_ + 2 * pair;
    float x1 = (float)x[base], x2 = (float)x[base + 1];
    x[base]     = (_Float16)((x1 * cs - x2 * sn) * scale);
    x[base + 1] = (_Float16)((x2 * cs + x1 * sn) * scale);
}

// ---------------------------------------------------------------- V transpose: fused[.,2048+h*128+dv] -> [B][H][128][S]
__global__ __launch_bounds__(256) void k_vtrans(const _Float16* __restrict__ vb,
                                                _Float16* __restrict__ Vt) {
    int st = blockIdx.x, dt = blockIdx.y, bh = blockIdx.z;
    int hh = bh & 15, b = bh >> 4;
    __shared__ __attribute__((aligned(16))) _Float16 Ts[64][72];
    int t = threadIdx.x;
    const _Float16* src = vb + (size_t)(b * S_ + st * 64) * NF_ + 2048 + hh * DV_ + dt * 64;
    #pragma unroll
    for (int c = 0; c < 2; c++) {
        int chunk = c * 256 + t;
        int r = chunk >> 3, co = (chunk & 7) * 8;
        *(f16x8*)&Ts[r][co] = *(const f16x8*)(src + (size_t)r * NF_ + co);
    }
    __syncthreads();
    _Float16* dst = Vt + ((size_t)bh * DV_ + dt * 64) * S_ + st * 64;
    #pragma unroll
    for (int c = 0; c < 2; c++) {
        int chunk = c * 256 + t;
        int dr = chunk >> 3, so = (chunk & 7) * 8;
        f16x8 val;
        #pragma unroll
        for (int j = 0; j < 8; j++) val[j] = Ts[so + j][dr];
        *(f16x8*)(dst + (size_t)dr * S_ + so) = val;
    }
}

// ---------------------------------------------------------------- MFMA retention attention (bank-swizzled LDS)
__global__ __launch_bounds__(256) void k_attn(const _Float16* __restrict__ qkvg,
                                              const _Float16* __restrict__ Vt,
                                              float* __restrict__ of) {
    int nt = blockIdx.x, bh = blockIdx.y;
    int hh = bh & 15, b = bh >> 4;
    int t = threadIdx.x, w = t >> 6, lane = t & 63;
    int quad = lane >> 4, l16 = lane & 15;
    int n0 = nt * 64;

    __shared__ __attribute__((aligned(16))) _Float16 Qs[64 * 64];
    __shared__ __attribute__((aligned(16))) _Float16 Ks[64 * 64];
    __shared__ __attribute__((aligned(16))) _Float16 Vs[128 * 64];
    __shared__ __attribute__((aligned(16))) _Float16 Ss[64 * 64];

    const _Float16* qg = qkvg + (size_t)(b * S_ + n0) * NF_ + hh * DK_;
    const _Float16* kg = qkvg + (size_t)(b * S_) * NF_ + 1024 + hh * DK_;
    const _Float16* vg = Vt + (size_t)bh * DV_ * S_;

    #pragma unroll
    for (int c = 0; c < 2; c++) {
        int chunk = c * 256 + t;
        int r = chunk >> 3, cg = chunk & 7;
        int ko = (cg ^ (r & 7)) * 8;
        gl2lds16(qg + (size_t)r * NF_ + ko, Qs + chunk * 8);
    }
    double gd   = 1.0 - exp2((double)(-5 - hh));
    double l2gd = log2(gd);
    float  l2g  = (float)l2gd;
    float rn[4];
    #pragma unroll
    for (int r = 0; r < 4; r++) {
        int n = n0 + w * 16 + quad * 4 + r;
        double rowsum = (1.0 - exp2(l2gd * (double)(n + 1))) / (1.0 - gd);
        rn[r] = (float)(1.0 / sqrt(rowsum));
    }
    int ra = w * 16 + l16;
    const f16x8* qp0 = (const f16x8*)&Qs[ra * 64 + (( quad      ^ (ra & 7)) * 8)];
    const f16x8* qp1 = (const f16x8*)&Qs[ra * 64 + (((quad + 4) ^ (ra & 7)) * 8)];
    const f16x8* sp0 = (const f16x8*)&Ss[ra * 64 + (( quad      ^ (ra & 7)) * 8)];
    const f16x8* sp1 = (const f16x8*)&Ss[ra * 64 + (((quad + 4) ^ (ra & 7)) * 8)];
    const f16x8* kp0[4]; const f16x8* kp1[4];
    const f16x8* vp0[8]; const f16x8* vp1[8];
    #pragma unroll
    for (int j = 0; j < 4; j++) {
        int rb = j * 16 + l16;
        kp0[j] = (const f16x8*)&Ks[rb * 64 + (( quad      ^ (rb & 7)) * 8)];
        kp1[j] = (const f16x8*)&Ks[rb * 64 + (((quad + 4) ^ (rb & 7)) * 8)];
    }
    #pragma unroll
    for (int j = 0; j < 8; j++) {
        int rv = j * 16 + l16;
        vp0[j] = (const f16x8*)&Vs[rv * 64 + (( quad      ^ (rv & 7)) * 8)];
        vp1[j] = (const f16x8*)&Vs[rv * 64 + (((quad + 4) ^ (rv & 7)) * 8)];
    }
    f32x4 oacc[8] = {};
    float absAcc[4] = {};

    for (int mt = 0; mt <= nt; mt++) {
        int m0 = mt * 64;
        __syncthreads();
        #pragma unroll
        for (int c = 0; c < 2; c++) {
            int chunk = c * 256 + t;
            int r = chunk >> 3, cg = chunk & 7;
            int ko = (cg ^ (r & 7)) * 8;
            gl2lds16(kg + (size_t)(m0 + r) * NF_ + ko, Ks + chunk * 8);
        }
        #pragma unroll
        for (int c = 0; c < 4; c++) {
            int chunk = c * 256 + t;
            int r = chunk >> 3, cg = chunk & 7;
            int ko = (cg ^ (r & 7)) * 8;
            gl2lds16(vg + (size_t)r * S_ + m0 + ko, Vs + chunk * 8);
        }
        __syncthreads();
        f16x8 a0 = *qp0, a1 = *qp1;
        f32x4 sacc[4] = {};
        #pragma unroll
        for (int j = 0; j < 4; j++) {
            sacc[j] = MFMA16(a0, *kp0[j], sacc[j]);
            sacc[j] = MFMA16(a1, *kp1[j], sacc[j]);
        }
        #pragma unroll
        for (int j = 0; j < 4; j++) {
            int m = m0 + j * 16 + l16;
            #pragma unroll
            for (int r = 0; r < 4; r++) {
                int n = n0 + w * 16 + quad * 4 + r;
                float dm = (n >= m) ? exp2f((float)(n - m) * l2g) * rn[r] : 0.0f;
                float sv = sacc[j][r] * dm;
                absAcc[r] += fabsf(sv);
                int rowS = w * 16 + quad * 4 + r;
                int colS = j * 16 + l16;
                Ss[rowS * 64 + ((((colS >> 3) ^ (rowS & 7)) << 3) | (colS & 7))] = (_Float16)sv;
            }
        }
        __syncthreads();
        f16x8 s0 = *sp0, s1 = *sp1;
        #pragma unroll
        for (int j = 0; j < 8; j++) {
            oacc[j] = MFMA16(s0, *vp0[j], oacc[j]);
            oacc[j] = MFMA16(s1, *vp1[j], oacc[j]);
        }
    }
    #pragma unroll
    for (int r = 0; r < 4; r++) {
        float s_ = absAcc[r];
        #pragma unroll
        for (int off = 1; off < 16; off <<= 1) s_ += __shfl_xor(s_, off, 64);
        absAcc[r] = s_;
    }
    #pragma unroll
    for (int r = 0; r < 4; r++) {
        int n = n0 + w * 16 + quad * 4 + r;
        float sc = 1.0f / fmaxf(absAcc[r], 1.0f);
        float* og = of + (size_t)(b * S_ + n) * (H_ * DV_) + hh * DV_;
        #pragma unroll
        for (int j = 0; j < 8; j++)
            og[j * 16 + l16] = oacc[j][r] * sc;
    }
}

// ---------------------------------------------------------------- RMS over 128 + silu gate: fp32 o, f16 g(fused) -> f16
__global__ __launch_bounds__(256) void k_rmsgate(const float* __restrict__ o,
                                                 const _Float16* __restrict__ qkvg,
                                                 _Float16* __restrict__ out) {
    int row = blockIdx.x * 2 + (threadIdx.x >> 7);   // row in [0, B*S*H)
    int tc = threadIdx.x & 127;
    int bs = row >> 4, hh = row & 15;
    size_t obase = (size_t)row * 128 + tc;
    float val = o[obase];
    float gv  = (float)qkvg[(size_t)bs * NF_ + 4096 + hh * DV_ + tc];
    float ss = val * val;
    #pragma unroll
    for (int off = 32; off > 0; off >>= 1) ss += __shfl_down(ss, off, 64);
    __shared__ float sm[4];
    int wv = threadIdx.x >> 6;
    if ((threadIdx.x & 63) == 0) sm[wv] = ss;
    __syncthreads();
    int rw = (threadIdx.x >> 7) * 2;
    ss = sm[rw] + sm[rw + 1];
    float rms = 1.0f / sqrtf(ss * (1.0f / 128.0f) + 1e-6f);
    float sig = 1.0f / (1.0f + __expf(-gv));
    out[obase] = (_Float16)(gv * sig * val * rms);
}

// ---------------------------------------------------------------- final: 2-partial reduce + LN + logits (V=2) + log_softmax
__global__ __launch_bounds__(256) void k_final(const float* __restrict__ x,
                                               const float* __restrict__ p0,
                                               const float* __restrict__ p1,
                                               const float* __restrict__ s,
                                               const float* __restrict__ b,
                                               const float* __restrict__ Wout,
                                               float* __restrict__ out) {
    int row = blockIdx.x;
    int t = threadIdx.x;
    size_t base = (size_t)row * D_ + t * 4;
    float4 xv = *(const float4*)&x[base];
    {
        float4 a = *(const float4*)&p0[base];
        float4 c = *(const float4*)&p1[base];
        xv.x += a.x + c.x; xv.y += a.y + c.y;
        xv.z += a.z + c.z; xv.w += a.w + c.w;
    }
    float sum = xv.x + xv.y + xv.z + xv.w;
    float ssq = xv.x * xv.x + xv.y * xv.y + xv.z * xv.z + xv.w * xv.w;
    __shared__ float sm1[4], sm2[4];
    #pragma unroll
    for (int off = 32; off > 0; off >>= 1) {
        sum += __shfl_down(sum, off, 64);
        ssq += __shfl_down(ssq, off, 64);
    }
    int lane = t & 63, w = t >> 6;
    if (lane == 0) { sm1[w] = sum; sm2[w] = ssq; }
    __syncthreads();
    sum = sm1[0] + sm1[1] + sm1[2] + sm1[3];
    ssq = sm2[0] + sm2[1] + sm2[2] + sm2[3];
    float mean = sum * (1.0f / D_);
    float var  = ssq * (1.0f / D_) - mean * mean;
    float inv  = 1.0f / sqrtf(var + 1e-5f);
    float4 sv = *(const float4*)&s[t * 4];
    float4 bv = *(const float4*)&b[t * 4];
    float ln[4];
    ln[0] = (xv.x - mean) * inv * sv.x + bv.x;
    ln[1] = (xv.y - mean) * inv * sv.y + bv.y;
    ln[2] = (xv.z - mean) * inv * sv.z + bv.z;
    ln[3] = (xv.w - mean) * inv * sv.w + bv.w;
    float l0 = 0.0f, l1 = 0.0f;
    #pragma unroll
    for (int i = 0; i < 4; i++) {
        int d = t * 4 + i;
        l0 += ln[i] * Wout[d * 2 + 0];
        l1 += ln[i] * Wout[d * 2 + 1];
    }
    #pragma unroll
    for (int off = 32; off > 0; off >>= 1) {
        l0 += __shfl_down(l0, off, 64);
        l1 += __shfl_down(l1, off, 64);
    }
    __syncthreads();
    if (lane == 0) { sm1[w] = l0; sm2[w] = l1; }
    __syncthreads();
    if (t == 0) {
        l0 = sm1[0] + sm1[1] + sm1[2] + sm1[3];
        l1 = sm2[0] + sm2[1] + sm2[2] + sm2[3];
        float mx  = fmaxf(l0, l1);
        float lse = mx + logf(expf(l0 - mx) + expf(l1 - mx));
        out[(size_t)row * 2 + 0] = l0 - lse;
        out[(size_t)row * 2 + 1] = l1 - lse;
    }
}

// ---------------------------------------------------------------- launch
extern "C" void kernel_launch(void* const* d_in, const int* in_sizes, int n_in,
                              void* d_out, int out_size, void* d_ws, size_t ws_size,
                              hipStream_t stream) {
    const int*   tokens = (const int*)d_in[0];
    const float* emb    = (const float*)d_in[1];
    const float* Wq     = (const float*)d_in[2];
    const float* Wk     = (const float*)d_in[3];
    const float* Wv     = (const float*)d_in[4];
    const float* Wg     = (const float*)d_in[5];
    const float* Wo     = (const float*)d_in[6];
    const float* ln1_s  = (const float*)d_in[7];
    const float* ln1_b  = (const float*)d_in[8];
    const float* ln2_s  = (const float*)d_in[9];
    const float* ln2_b  = (const float*)d_in[10];
    const float* W1     = (const float*)d_in[11];
    const float* b1     = (const float*)d_in[12];
    const float* W2     = (const float*)d_in[13];
    const float* b2     = (const float*)d_in[14];
    const float* lnf_s  = (const float*)d_in[15];
    const float* lnf_b  = (const float*)d_in[16];
    const float* Wout   = (const float*)d_in[17];

    float* ws = (float*)d_ws;
    const size_t M1 = 1u << 20;
    // layout in float units (total 39M floats = 156 MB):
    float*     h    = ws;                              // [0,4M) fp32
    _Float16*  x1h  = (_Float16*)(ws + 4 * M1);        // [4M,6M) 4M f16
    _Float16*  whb  = (_Float16*)(ws + 6 * M1);        // [6M,14M) 16M f16 weights
    _Float16*  wQKVG= whb;                             // [6144][1024]
    _Float16*  woT  = whb + 6 * M1;                    // [1024][2048]
    _Float16*  w1T  = whb + 8 * M1;                    // [4096][1024]
    _Float16*  w2T  = whb + 12 * M1;                   // [1024][4096]
    _Float16*  qkvg = (_Float16*)(ws + 14 * M1);       // [14M,27M) [4096][6144] f16
    _Float16*  Vth  = (_Float16*)(ws + 27 * M1);       // [27M,31M) 8M f16
    float*     of   = ws + 31 * M1;                    // [31M,39M) fp32 [4096][2048]
    _Float16*  oh   = (_Float16*)(ws + 27 * M1);       // overlays Vth (dead after attn)
    _Float16*  f1h  = (_Float16*)(ws + 14 * M1);       // overlays qkvg (dead after rmsgate)
    float*     pb0  = ws + 31 * M1;                    // partials overlay `of` (dead after rmsgate)
    float*     pb1  = ws + 35 * M1;

    k_embed<<<16384, 256, 0, stream>>>(tokens, emb, h);

    for (int l = 0; l < L_; l++) {
        const float* pWq = Wq + (size_t)l * M1;
        const float* pWk = Wk + (size_t)l * M1;
        const float* pWv = Wv + (size_t)l * 2 * M1;
        const float* pWg = Wg + (size_t)l * 2 * M1;
        const float* pWo = Wo + (size_t)l * 2 * M1;
        const float* pW1 = W1 + (size_t)l * 4 * M1;
        const float* pW2 = W2 + (size_t)l * 4 * M1;

        k_wcast<<<dim3(32, 32),  256, 0, stream>>>(pWq, wQKVG,          1024, 1024);
        k_wcast<<<dim3(32, 32),  256, 0, stream>>>(pWk, wQKVG + 1 * M1, 1024, 1024);
        k_wcast<<<dim3(64, 32),  256, 0, stream>>>(pWv, wQKVG + 2 * M1, 1024, 2048);
        k_wcast<<<dim3(64, 32),  256, 0, stream>>>(pWg, wQKVG + 4 * M1, 1024, 2048);
        k_wcast<<<dim3(32, 64),  256, 0, stream>>>(pWo, woT, 2048, 1024);
        k_wcast<<<dim3(128, 32), 256, 0, stream>>>(pW1, w1T, 1024, 4096);
        k_wcast<<<dim3(32, 128), 256, 0, stream>>>(pW2, w2T, 4096, 1024);

        // ln1: layer 0 has no pending partials; layers 1,2 fold in prev layer's W2 partials
        k_ln<<<4096, 256, 0, stream>>>(h, pb0, pb1, (l == 0) ? 0 : 1,
                                       ln1_s + l * D_, ln1_b + l * D_, x1h);
        // fused QKVG: [4096][6144] = x1h @ wQKVG^T   (48*32 = 1536 tiles)
        k_gemm_mfma<<<dim3(1536), 256, 0, stream>>>(x1h, wQKVG, nullptr, nullptr, qkvg,
                                                    4096, NF_, 1024, 8);
        k_rope<<<8192, 256, 0, stream>>>(qkvg, 1.0f);            // q cols [0,1024)
        k_rope<<<8192, 256, 0, stream>>>(qkvg + 1024, 0.125f);   // k cols [1024,2048)
        k_vtrans<<<dim3(16, 2, 64), 256, 0, stream>>>(qkvg, Vth);
        k_attn<<<dim3(16, 64), 256, 0, stream>>>(qkvg, Vth, of);
        k_rmsgate<<<32768, 256, 0, stream>>>(of, qkvg, oh);
        // Wo partials (split-K x2, Kc=1024): pb[z] = oh @ woT_chunk
        k_gemm_splitk<<<dim3(256, 1, 2), 256, 0, stream>>>(oh, woT, nullptr, pb0,
                                                           4096, 1024, 2048, 1024);
        // ln2 folds Wo partials into h
        k_ln<<<4096, 256, 0, stream>>>(h, pb0, pb1, 1,
                                       ln2_s + l * D_, ln2_b + l * D_, x1h);
        k_gemm_mfma<<<dim3(1024), 256, 0, stream>>>(x1h, w1T, b1 + l * FFN_, nullptr, f1h,
                                                    4096, 4096, 1024, 2 | 4 | 8);
        // W2 partials (split-K x2, Kc=2048): folded by next ln1 or k_final
        k_gemm_splitk<<<dim3(256, 1, 2), 256, 0, stream>>>(f1h, w2T, b2 + l * D_, pb0,
                                                           4096, 1024, 4096, 2048);
    }
    k_final<<<4096, 256, 0, stream>>>(h, pb0, pb1, lnf_s, lnf_b, Wout, (float*)d_out);
}

// Round 7
// 1442.707 us; speedup vs baseline: 7.0941x; 1.0114x over previous
//
#include <hip/hip_runtime.h>
#include <hip/hip_bf16.h>
#include <math.h>
#include <stdint.h>

#define D_   1024
#define H_   16
#define DK_  64
#define DV_  128
#define L_   3
#define FFN_ 4096
#define S_   1024
#define B_   4
#define NF_  6144   // fused QKVG output width

typedef __attribute__((ext_vector_type(8))) _Float16 f16x8;
typedef __attribute__((ext_vector_type(4))) _Float16 f16x4;
typedef __attribute__((ext_vector_type(4))) float f32x4;

__device__ __forceinline__ void gl2lds16(const void* g, void* l) {
    __builtin_amdgcn_global_load_lds(
        (const __attribute__((address_space(1))) void*)(uintptr_t)g,
        (__attribute__((address_space(3))) void*)(uintptr_t)l, 16, 0, 0);
}
#define MFMA16(a,b,c) __builtin_amdgcn_mfma_f32_16x16x32_f16(a,b,c,0,0,0)

// fast gelu (tanh-approx, sigmoid form): 0.5v(1+tanh(y)) == v*sigmoid(2y), hw v_exp
__device__ __forceinline__ float fast_gelu(float v) {
    float y = 1.5957691216f * (v + 0.044715f * v * v * v);
    return v * (1.0f / (1.0f + __expf(-y)));
}

// supertile swizzle: pid -> (m0, n0), 8x8 block groups for L2 locality.
__device__ __forceinline__ void tile_swizzle(int pid, int N, int* m0, int* n0) {
    int nb = N >> 7;
    int sgn = nb >> 3;
    int sid = pid >> 6, wi = pid & 63;
    int smi = sid / sgn, sni = sid - smi * sgn;
    *m0 = ((smi << 3) + (wi >> 3)) << 7;
    *n0 = ((sni << 3) + (wi & 7)) << 7;
}

// ---------------------------------------------------------------- embed (fp32 h)
__global__ __launch_bounds__(256) void k_embed(const int* __restrict__ tokens,
                                               const float* __restrict__ emb,
                                               float* __restrict__ h) {
    int i = blockIdx.x * 256 + threadIdx.x;
    int d  = i & (D_ - 1);
    int bs = i >> 10;
    int s  = bs & (S_ - 1);
    int b  = bs >> 10;
    int tok = (s == 0) ? 0 : tokens[b * S_ + s - 1];
    h[i] = emb[tok * D_ + d] * 32.0f;
}

// ---------------------------------------------------------------- layernorm -> fp16
__global__ __launch_bounds__(256) void k_ln(const float* __restrict__ x,
                                            const float* __restrict__ s,
                                            const float* __restrict__ b,
                                            _Float16* __restrict__ y) {
    int row = blockIdx.x;
    int t = threadIdx.x;
    size_t base = (size_t)row * D_ + t * 4;
    float4 xv = *(const float4*)&x[base];
    float sum = xv.x + xv.y + xv.z + xv.w;
    float ssq = xv.x * xv.x + xv.y * xv.y + xv.z * xv.z + xv.w * xv.w;
    __shared__ float sm1[4], sm2[4];
    #pragma unroll
    for (int off = 32; off > 0; off >>= 1) {
        sum += __shfl_down(sum, off, 64);
        ssq += __shfl_down(ssq, off, 64);
    }
    int lane = t & 63, w = t >> 6;
    if (lane == 0) { sm1[w] = sum; sm2[w] = ssq; }
    __syncthreads();
    sum = sm1[0] + sm1[1] + sm1[2] + sm1[3];
    ssq = sm2[0] + sm2[1] + sm2[2] + sm2[3];
    float mean = sum * (1.0f / D_);
    float var  = ssq * (1.0f / D_) - mean * mean;
    float inv  = 1.0f / sqrtf(var + 1e-5f);
    float4 sv = *(const float4*)&s[t * 4];
    float4 bv = *(const float4*)&b[t * 4];
    f16x4 o;
    o.x = (_Float16)((xv.x - mean) * inv * sv.x + bv.x);
    o.y = (_Float16)((xv.y - mean) * inv * sv.y + bv.y);
    o.z = (_Float16)((xv.z - mean) * inv * sv.z + bv.z);
    o.w = (_Float16)((xv.w - mean) * inv * sv.w + bv.w);
    *(f16x4*)&y[base] = o;
}

// ---------------------------------------------------------------- fused QKVG weight cast: 4 segments in one launch
// fp32 [K=1024][N] -> f16 [N][1024] at segment offsets in dst
__global__ __launch_bounds__(256) void k_wcast4(const float* __restrict__ wq,
                                                const float* __restrict__ wk,
                                                const float* __restrict__ wv,
                                                const float* __restrict__ wg,
                                                _Float16* __restrict__ dst) {
    int bid = blockIdx.x;
    const float* src; _Float16* out; int N; int local;
    if (bid < 1024)      { src = wq; out = dst;                 N = 1024; local = bid; }
    else if (bid < 2048) { src = wk; out = dst + 1024 * 1024;   N = 1024; local = bid - 1024; }
    else if (bid < 4096) { src = wv; out = dst + 2*1024*1024;   N = 2048; local = bid - 2048; }
    else                 { src = wg; out = dst + 4*1024*1024;   N = 2048; local = bid - 4096; }
    int ntiles = N >> 5;
    int n0 = (local % ntiles) * 32, k0 = (local / ntiles) * 32;
    __shared__ float Ts[32][33];
    int t = threadIdx.x;
    #pragma unroll
    for (int c = 0; c < 4; c++) {
        int e = c * 256 + t; int kr = e >> 5, nc = e & 31;
        Ts[kr][nc] = src[(size_t)(k0 + kr) * N + n0 + nc];
    }
    __syncthreads();
    #pragma unroll
    for (int c = 0; c < 4; c++) {
        int e = c * 256 + t; int nr = e >> 5, kc = e & 31;
        out[(size_t)(n0 + nr) * 1024 + k0 + kc] = (_Float16)Ts[kc][nr];
    }
}

// ---------------------------------------------------------------- weight cast+transpose: fp32 [K][N] -> fp16 [N][K]
__global__ __launch_bounds__(256) void k_wcast(const float* __restrict__ in,
                                               _Float16* __restrict__ out,
                                               int K, int N) {
    __shared__ float Ts[32][33];
    int n0 = blockIdx.x * 32, k0 = blockIdx.y * 32;
    int t = threadIdx.x;
    #pragma unroll
    for (int c = 0; c < 4; c++) {
        int e = c * 256 + t; int kr = e >> 5, nc = e & 31;
        Ts[kr][nc] = in[(size_t)(k0 + kr) * N + n0 + nc];
    }
    __syncthreads();
    #pragma unroll
    for (int c = 0; c < 4; c++) {
        int e = c * 256 + t; int nr = e >> 5, kc = e & 31;
        out[(size_t)(n0 + nr) * K + k0 + kc] = (_Float16)Ts[kc][nr];
    }
}

// ---------------------------------------------------------------- MFMA GEMM (128x128 tile): C = A @ Bt^T, f16 out
// flags: 2=+bias, 4=gelu, 16=rope on cols<2048 (QKVG): pairs via shfl_xor(1), k-scale 0.125
__global__ __launch_bounds__(256) void k_gemm_mfma(
    const _Float16* __restrict__ A, const _Float16* __restrict__ Bt,
    const float* __restrict__ bias, _Float16* __restrict__ Ch,
    int M, int N, int K, int flags)
{
    __shared__ __attribute__((aligned(16))) _Float16 As[128 * 32];
    __shared__ __attribute__((aligned(16))) _Float16 Bs[128 * 32];
    int t = threadIdx.x;
    int m0, n0;
    tile_swizzle(blockIdx.x, N, &m0, &n0);
    int w = t >> 6, lane = t & 63;
    int quad = lane >> 4, l16 = lane & 15;
    int wm = (w >> 1) * 64, wn = (w & 1) * 64;
    const f16x8* aptr[4]; const f16x8* bptr[4];
    #pragma unroll
    for (int i = 0; i < 4; i++) {
        int ra = wm + i * 16 + l16;
        aptr[i] = (const f16x8*)&As[ra * 32 + ((quad ^ ((ra >> 1) & 3)) * 8)];
        int rb = wn + i * 16 + l16;
        bptr[i] = (const f16x8*)&Bs[rb * 32 + ((quad ^ ((rb >> 1) & 3)) * 8)];
    }
    f32x4 acc[4][4] = {};
    for (int k0 = 0; k0 < K; k0 += 32) {
        __syncthreads();
        #pragma unroll
        for (int c = 0; c < 2; c++) {
            int chunk = c * 256 + t;
            int row = chunk >> 2, cg = chunk & 3;
            int ko = (cg ^ ((row >> 1) & 3)) * 8;
            gl2lds16(A  + (size_t)(m0 + row) * K + k0 + ko, As + chunk * 8);
            gl2lds16(Bt + (size_t)(n0 + row) * K + k0 + ko, Bs + chunk * 8);
        }
        __syncthreads();
        f16x8 af[4], bfr[4];
        #pragma unroll
        for (int i = 0; i < 4; i++) af[i] = *aptr[i];
        #pragma unroll
        for (int j = 0; j < 4; j++) bfr[j] = *bptr[j];
        #pragma unroll
        for (int i = 0; i < 4; i++)
            #pragma unroll
            for (int j = 0; j < 4; j++)
                acc[i][j] = MFMA16(af[i], bfr[j], acc[i][j]);
    }
    #pragma unroll
    for (int i = 0; i < 4; i++) {
        #pragma unroll
        for (int r = 0; r < 4; r++) {
            int row = m0 + wm + i * 16 + quad * 4 + r;
            #pragma unroll
            for (int j = 0; j < 4; j++) {
                int col = n0 + wn + j * 16 + l16;
                float v = acc[i][j][r];
                if (flags & 2) v += bias[col];
                if (flags & 4) v = fast_gelu(v);
                if (flags & 16) {
                    if (col < 2048) {               // uniform across wave (16-col groups)
                        int p = (col & 63) >> 1;
                        int srow = row & (S_ - 1);
                        float ang = __expf(-(float)p * (1.0f / 31.0f) * 9.210340372f);
                        float ph = (float)srow * ang;
                        float sn, cs;
                        __sincosf(ph, &sn, &cs);
                        float partner = __shfl_xor(v, 1, 64);
                        v = (l16 & 1) ? (v * cs + partner * sn)
                                      : (v * cs - partner * sn);
                        if (col >= 1024) v *= 0.125f;   // DK^-0.5 for k
                    }
                }
                Ch[(size_t)row * N + col] = (_Float16)v;
            }
        }
    }
}

// ---------------------------------------------------------------- direct RMW GEMM (64x128 tile): Cf += A @ Bt^T (+bias)
// grid (N/128, M/64). Non-atomic: each output written by exactly one block.
__global__ __launch_bounds__(256) void k_gemm_rmw(
    const _Float16* __restrict__ A, const _Float16* __restrict__ Bt,
    const float* __restrict__ bias, float* __restrict__ Cf,
    int M, int N, int K)
{
    __shared__ __attribute__((aligned(16))) _Float16 As[64 * 32];
    __shared__ __attribute__((aligned(16))) _Float16 Bs[128 * 32];
    int t = threadIdx.x;
    int n0 = blockIdx.x * 128, m0 = blockIdx.y * 64;
    int w = t >> 6, lane = t & 63;
    int quad = lane >> 4, l16 = lane & 15;
    int wm = (w >> 1) * 32, wn = (w & 1) * 64;
    const f16x8* aptr[2]; const f16x8* bptr[4];
    #pragma unroll
    for (int i = 0; i < 2; i++) {
        int ra = wm + i * 16 + l16;
        aptr[i] = (const f16x8*)&As[ra * 32 + ((quad ^ ((ra >> 1) & 3)) * 8)];
    }
    #pragma unroll
    for (int j = 0; j < 4; j++) {
        int rb = wn + j * 16 + l16;
        bptr[j] = (const f16x8*)&Bs[rb * 32 + ((quad ^ ((rb >> 1) & 3)) * 8)];
    }
    f32x4 acc[2][4] = {};
    for (int k0 = 0; k0 < K; k0 += 32) {
        __syncthreads();
        {   // A: 64x32 = 256 chunks (1/thread)
            int row = t >> 2, cg = t & 3;
            int ko = (cg ^ ((row >> 1) & 3)) * 8;
            gl2lds16(A + (size_t)(m0 + row) * K + k0 + ko, As + t * 8);
        }
        #pragma unroll
        for (int c = 0; c < 2; c++) {  // B: 128x32 = 512 chunks (2/thread)
            int chunk = c * 256 + t;
            int row = chunk >> 2, cg = chunk & 3;
            int ko = (cg ^ ((row >> 1) & 3)) * 8;
            gl2lds16(Bt + (size_t)(n0 + row) * K + k0 + ko, Bs + chunk * 8);
        }
        __syncthreads();
        f16x8 af[2], bfr[4];
        #pragma unroll
        for (int i = 0; i < 2; i++) af[i] = *aptr[i];
        #pragma unroll
        for (int j = 0; j < 4; j++) bfr[j] = *bptr[j];
        #pragma unroll
        for (int i = 0; i < 2; i++)
            #pragma unroll
            for (int j = 0; j < 4; j++)
                acc[i][j] = MFMA16(af[i], bfr[j], acc[i][j]);
    }
    #pragma unroll
    for (int i = 0; i < 2; i++) {
        #pragma unroll
        for (int r = 0; r < 4; r++) {
            int row = m0 + wm + i * 16 + quad * 4 + r;
            #pragma unroll
            for (int j = 0; j < 4; j++) {
                int col = n0 + wn + j * 16 + l16;
                float v = acc[i][j][r];
                if (bias) v += bias[col];
                size_t idx = (size_t)row * N + col;
                Cf[idx] += v;
            }
        }
    }
}

// ---------------------------------------------------------------- V transpose: fused[.,2048+h*128+dv] -> [B][H][128][S]
__global__ __launch_bounds__(256) void k_vtrans(const _Float16* __restrict__ vb,
                                                _Float16* __restrict__ Vt) {
    int st = blockIdx.x, dt = blockIdx.y, bh = blockIdx.z;
    int hh = bh & 15, b = bh >> 4;
    __shared__ __attribute__((aligned(16))) _Float16 Ts[64][72];
    int t = threadIdx.x;
    const _Float16* src = vb + (size_t)(b * S_ + st * 64) * NF_ + 2048 + hh * DV_ + dt * 64;
    #pragma unroll
    for (int c = 0; c < 2; c++) {
        int chunk = c * 256 + t;
        int r = chunk >> 3, co = (chunk & 7) * 8;
        *(f16x8*)&Ts[r][co] = *(const f16x8*)(src + (size_t)r * NF_ + co);
    }
    __syncthreads();
    _Float16* dst = Vt + ((size_t)bh * DV_ + dt * 64) * S_ + st * 64;
    #pragma unroll
    for (int c = 0; c < 2; c++) {
        int chunk = c * 256 + t;
        int dr = chunk >> 3, so = (chunk & 7) * 8;
        f16x8 val;
        #pragma unroll
        for (int j = 0; j < 8; j++) val[j] = Ts[so + j][dr];
        *(f16x8*)(dst + (size_t)dr * S_ + so) = val;
    }
}

// ---------------------------------------------------------------- MFMA retention attention + fused RMS/silu-gate epilogue
// q,k,g from fused qkvg buffer; Vt: [B][H][128][S] f16; out oh: f16 [B*S][H*128]
__global__ __launch_bounds__(256) void k_attn(const _Float16* __restrict__ qkvg,
                                              const _Float16* __restrict__ Vt,
                                              _Float16* __restrict__ oh) {
    int nt = blockIdx.x, bh = blockIdx.y;
    int hh = bh & 15, b = bh >> 4;
    int t = threadIdx.x, w = t >> 6, lane = t & 63;
    int quad = lane >> 4, l16 = lane & 15;
    int n0 = nt * 64;

    __shared__ __attribute__((aligned(16))) _Float16 Qs[64 * 64];
    __shared__ __attribute__((aligned(16))) _Float16 Ks[64 * 64];
    __shared__ __attribute__((aligned(16))) _Float16 Vs[128 * 64];
    __shared__ __attribute__((aligned(16))) _Float16 Ss[64 * 64];

    const _Float16* qg = qkvg + (size_t)(b * S_ + n0) * NF_ + hh * DK_;
    const _Float16* kg = qkvg + (size_t)(b * S_) * NF_ + 1024 + hh * DK_;
    const _Float16* vg = Vt + (size_t)bh * DV_ * S_;

    #pragma unroll
    for (int c = 0; c < 2; c++) {
        int chunk = c * 256 + t;
        int r = chunk >> 3, cg = chunk & 7;
        int ko = (cg ^ (r & 7)) * 8;
        gl2lds16(qg + (size_t)r * NF_ + ko, Qs + chunk * 8);
    }
    double gd   = 1.0 - exp2((double)(-5 - hh));
    double l2gd = log2(gd);
    float  l2g  = (float)l2gd;
    float rn[4];
    #pragma unroll
    for (int r = 0; r < 4; r++) {
        int n = n0 + w * 16 + quad * 4 + r;
        double rowsum = (1.0 - exp2(l2gd * (double)(n + 1))) / (1.0 - gd);
        rn[r] = (float)(1.0 / sqrt(rowsum));
    }
    int ra = w * 16 + l16;
    const f16x8* qp0 = (const f16x8*)&Qs[ra * 64 + (( quad      ^ (ra & 7)) * 8)];
    const f16x8* qp1 = (const f16x8*)&Qs[ra * 64 + (((quad + 4) ^ (ra & 7)) * 8)];
    const f16x8* sp0 = (const f16x8*)&Ss[ra * 64 + (( quad      ^ (ra & 7)) * 8)];
    const f16x8* sp1 = (const f16x8*)&Ss[ra * 64 + (((quad + 4) ^ (ra & 7)) * 8)];
    const f16x8* kp0[4]; const f16x8* kp1[4];
    const f16x8* vp0[8]; const f16x8* vp1[8];
    #pragma unroll
    for (int j = 0; j < 4; j++) {
        int rb = j * 16 + l16;
        kp0[j] = (const f16x8*)&Ks[rb * 64 + (( quad      ^ (rb & 7)) * 8)];
        kp1[j] = (const f16x8*)&Ks[rb * 64 + (((quad + 4) ^ (rb & 7)) * 8)];
    }
    #pragma unroll
    for (int j = 0; j < 8; j++) {
        int rv = j * 16 + l16;
        vp0[j] = (const f16x8*)&Vs[rv * 64 + (( quad      ^ (rv & 7)) * 8)];
        vp1[j] = (const f16x8*)&Vs[rv * 64 + (((quad + 4) ^ (rv & 7)) * 8)];
    }
    f32x4 oacc[8] = {};
    float absAcc[4] = {};

    for (int mt = 0; mt <= nt; mt++) {
        int m0 = mt * 64;
        __syncthreads();
        #pragma unroll
        for (int c = 0; c < 2; c++) {
            int chunk = c * 256 + t;
            int r = chunk >> 3, cg = chunk & 7;
            int ko = (cg ^ (r & 7)) * 8;
            gl2lds16(kg + (size_t)(m0 + r) * NF_ + ko, Ks + chunk * 8);
        }
        #pragma unroll
        for (int c = 0; c < 4; c++) {
            int chunk = c * 256 + t;
            int r = chunk >> 3, cg = chunk & 7;
            int ko = (cg ^ (r & 7)) * 8;
            gl2lds16(vg + (size_t)r * S_ + m0 + ko, Vs + chunk * 8);
        }
        __syncthreads();
        f16x8 a0 = *qp0, a1 = *qp1;
        f32x4 sacc[4] = {};
        #pragma unroll
        for (int j = 0; j < 4; j++) {
            sacc[j] = MFMA16(a0, *kp0[j], sacc[j]);
            sacc[j] = MFMA16(a1, *kp1[j], sacc[j]);
        }
        #pragma unroll
        for (int j = 0; j < 4; j++) {
            int m = m0 + j * 16 + l16;
            #pragma unroll
            for (int r = 0; r < 4; r++) {
                int n = n0 + w * 16 + quad * 4 + r;
                float dm = (n >= m) ? exp2f((float)(n - m) * l2g) * rn[r] : 0.0f;
                float sv = sacc[j][r] * dm;
                absAcc[r] += fabsf(sv);
                int rowS = w * 16 + quad * 4 + r;
                int colS = j * 16 + l16;
                Ss[rowS * 64 + ((((colS >> 3) ^ (rowS & 7)) << 3) | (colS & 7))] = (_Float16)sv;
            }
        }
        __syncthreads();
        f16x8 s0 = *sp0, s1 = *sp1;
        #pragma unroll
        for (int j = 0; j < 8; j++) {
            oacc[j] = MFMA16(s0, *vp0[j], oacc[j]);
            oacc[j] = MFMA16(s1, *vp1[j], oacc[j]);
        }
    }
    // |S| row sums across the 16 col-lanes
    #pragma unroll
    for (int r = 0; r < 4; r++) {
        float s_ = absAcc[r];
        #pragma unroll
        for (int off = 1; off < 16; off <<= 1) s_ += __shfl_xor(s_, off, 64);
        absAcc[r] = s_;
    }
    // fused epilogue: qk-normalize, RMS over 128, silu(g)-gate, f16 store
    #pragma unroll
    for (int r = 0; r < 4; r++) {
        int n = n0 + w * 16 + quad * 4 + r;
        float sc = 1.0f / fmaxf(absAcc[r], 1.0f);
        float vals[8];
        float ssq = 0.0f;
        #pragma unroll
        for (int j = 0; j < 8; j++) {
            vals[j] = oacc[j][r] * sc;
            ssq += vals[j] * vals[j];
        }
        #pragma unroll
        for (int off = 1; off < 16; off <<= 1) ssq += __shfl_xor(ssq, off, 64);
        float rms = 1.0f / sqrtf(ssq * (1.0f / 128.0f) + 1e-6f);
        const _Float16* gg = qkvg + (size_t)(b * S_ + n) * NF_ + 4096 + hh * DV_;
        _Float16* og = oh + (size_t)(b * S_ + n) * (H_ * DV_) + hh * DV_;
        #pragma unroll
        for (int j = 0; j < 8; j++) {
            float gv = (float)gg[j * 16 + l16];
            float sig = 1.0f / (1.0f + __expf(-gv));
            og[j * 16 + l16] = (_Float16)(gv * sig * vals[j] * rms);
        }
    }
}

// ---------------------------------------------------------------- final LN + logits (V=2) + log_softmax
__global__ __launch_bounds__(256) void k_final(const float* __restrict__ x,
                                               const float* __restrict__ s,
                                               const float* __restrict__ b,
                                               const float* __restrict__ Wout,
                                               float* __restrict__ out) {
    int row = blockIdx.x;
    int t = threadIdx.x;
    size_t base = (size_t)row * D_ + t * 4;
    float4 xv = *(const float4*)&x[base];
    float sum = xv.x + xv.y + xv.z + xv.w;
    float ssq = xv.x * xv.x + xv.y * xv.y + xv.z * xv.z + xv.w * xv.w;
    __shared__ float sm1[4], sm2[4];
    #pragma unroll
    for (int off = 32; off > 0; off >>= 1) {
        sum += __shfl_down(sum, off, 64);
        ssq += __shfl_down(ssq, off, 64);
    }
    int lane = t & 63, w = t >> 6;
    if (lane == 0) { sm1[w] = sum; sm2[w] = ssq; }
    __syncthreads();
    sum = sm1[0] + sm1[1] + sm1[2] + sm1[3];
    ssq = sm2[0] + sm2[1] + sm2[2] + sm2[3];
    float mean = sum * (1.0f / D_);
    float var  = ssq * (1.0f / D_) - mean * mean;
    float inv  = 1.0f / sqrtf(var + 1e-5f);
    float4 sv = *(const float4*)&s[t * 4];
    float4 bv = *(const float4*)&b[t * 4];
    float ln[4];
    ln[0] = (xv.x - mean) * inv * sv.x + bv.x;
    ln[1] = (xv.y - mean) * inv * sv.y + bv.y;
    ln[2] = (xv.z - mean) * inv * sv.z + bv.z;
    ln[3] = (xv.w - mean) * inv * sv.w + bv.w;
    float l0 = 0.0f, l1 = 0.0f;
    #pragma unroll
    for (int i = 0; i < 4; i++) {
        int d = t * 4 + i;
        l0 += ln[i] * Wout[d * 2 + 0];
        l1 += ln[i] * Wout[d * 2 + 1];
    }
    #pragma unroll
    for (int off = 32; off > 0; off >>= 1) {
        l0 += __shfl_down(l0, off, 64);
        l1 += __shfl_down(l1, off, 64);
    }
    __syncthreads();
    if (lane == 0) { sm1[w] = l0; sm2[w] = l1; }
    __syncthreads();
    if (t == 0) {
        l0 = sm1[0] + sm1[1] + sm1[2] + sm1[3];
        l1 = sm2[0] + sm2[1] + sm2[2] + sm2[3];
        float mx  = fmaxf(l0, l1);
        float lse = mx + logf(expf(l0 - mx) + expf(l1 - mx));
        out[(size_t)row * 2 + 0] = l0 - lse;
        out[(size_t)row * 2 + 1] = l1 - lse;
    }
}

// ---------------------------------------------------------------- launch
extern "C" void kernel_launch(void* const* d_in, const int* in_sizes, int n_in,
                              void* d_out, int out_size, void* d_ws, size_t ws_size,
                              hipStream_t stream) {
    const int*   tokens = (const int*)d_in[0];
    const float* emb    = (const float*)d_in[1];
    const float* Wq     = (const float*)d_in[2];
    const float* Wk     = (const float*)d_in[3];
    const float* Wv     = (const float*)d_in[4];
    const float* Wg     = (const float*)d_in[5];
    const float* Wo     = (const float*)d_in[6];
    const float* ln1_s  = (const float*)d_in[7];
    const float* ln1_b  = (const float*)d_in[8];
    const float* ln2_s  = (const float*)d_in[9];
    const float* ln2_b  = (const float*)d_in[10];
    const float* W1     = (const float*)d_in[11];
    const float* b1     = (const float*)d_in[12];
    const float* W2     = (const float*)d_in[13];
    const float* b2     = (const float*)d_in[14];
    const float* lnf_s  = (const float*)d_in[15];
    const float* lnf_b  = (const float*)d_in[16];
    const float* Wout   = (const float*)d_in[17];

    float* ws = (float*)d_ws;
    const size_t M1 = 1u << 20;
    // layout in float units (total 35M floats = 140 MB):
    float*     h    = ws;                              // [0,4M) fp32
    _Float16*  x1h  = (_Float16*)(ws + 4 * M1);        // [4M,6M) f16 [4096][1024]
    _Float16*  whb  = (_Float16*)(ws + 6 * M1);        // [6M,14M) f16 weights
    _Float16*  wQKVG= whb;                             // [6144][1024]
    _Float16*  woT  = whb + 6 * M1;                    // [1024][2048]
    _Float16*  w1T  = whb + 8 * M1;                    // [4096][1024]
    _Float16*  w2T  = whb + 12 * M1;                   // [1024][4096]
    _Float16*  qkvg = (_Float16*)(ws + 14 * M1);       // [14M,27M) f16 [4096][6144]
    _Float16*  Vth  = (_Float16*)(ws + 27 * M1);       // [27M,31M) f16 [64][128][1024]
    _Float16*  oh   = (_Float16*)(ws + 31 * M1);       // [31M,35M) f16 [4096][2048]
    _Float16*  f1h  = (_Float16*)(ws + 14 * M1);       // overlays qkvg (dead after attn)

    k_embed<<<16384, 256, 0, stream>>>(tokens, emb, h);

    for (int l = 0; l < L_; l++) {
        const float* pWq = Wq + (size_t)l * M1;
        const float* pWk = Wk + (size_t)l * M1;
        const float* pWv = Wv + (size_t)l * 2 * M1;
        const float* pWg = Wg + (size_t)l * 2 * M1;
        const float* pWo = Wo + (size_t)l * 2 * M1;
        const float* pW1 = W1 + (size_t)l * 4 * M1;
        const float* pW2 = W2 + (size_t)l * 4 * M1;

        k_wcast4<<<6144, 256, 0, stream>>>(pWq, pWk, pWv, pWg, wQKVG);
        k_wcast<<<dim3(32, 64),  256, 0, stream>>>(pWo, woT, 2048, 1024);
        k_wcast<<<dim3(128, 32), 256, 0, stream>>>(pW1, w1T, 1024, 4096);
        k_wcast<<<dim3(32, 128), 256, 0, stream>>>(pW2, w2T, 4096, 1024);

        k_ln<<<4096, 256, 0, stream>>>(h, ln1_s + l * D_, ln1_b + l * D_, x1h);
        // fused QKVG (rope fused in epilogue): [4096][6144] = x1h @ wQKVG^T
        k_gemm_mfma<<<dim3(1536), 256, 0, stream>>>(x1h, wQKVG, nullptr, qkvg,
                                                    4096, NF_, 1024, 16);
        k_vtrans<<<dim3(16, 2, 64), 256, 0, stream>>>(qkvg, Vth);
        k_attn<<<dim3(16, 64), 256, 0, stream>>>(qkvg, Vth, oh);
        // h += oh @ Wo  (direct RMW, 64x128 tiles, grid 512)
        k_gemm_rmw<<<dim3(8, 64), 256, 0, stream>>>(oh, woT, nullptr, h,
                                                    4096, 1024, 2048);
        k_ln<<<4096, 256, 0, stream>>>(h, ln2_s + l * D_, ln2_b + l * D_, x1h);
        k_gemm_mfma<<<dim3(1024), 256, 0, stream>>>(x1h, w1T, b1 + l * FFN_, f1h,
                                                    4096, 4096, 1024, 2 | 4);
        // h += f1h @ W2 + b2  (direct RMW)
        k_gemm_rmw<<<dim3(8, 64), 256, 0, stream>>>(f1h, w2T, b2 + l * D_, h,
                                                    4096, 1024, 4096);
    }
    k_final<<<4096, 256, 0, stream>>>(h, lnf_s, lnf_b, Wout, (float*)d_out);
}